// Round 4
// baseline (1060.474 us; speedup 1.0000x reference)
//
#include <hip/hip_runtime.h>
#include <hip/hip_bf16.h>
#include <math.h>

typedef __hip_bfloat16 bf16;
typedef __attribute__((ext_vector_type(8))) short short8;
typedef __attribute__((ext_vector_type(4))) float floatx4;

constexpr int Bc = 4, Sc = 1024, Dc = 2048, Hc = 16, HDc = 128, Ic = 8192;
constexpr int QKVLD = 3 * Dc;  // 6144

__device__ __forceinline__ float bf2f(bf16 x){ return __bfloat162float(x); }
__device__ __forceinline__ bf16 f2bf(float x){ return __float2bfloat16(x); }

__device__ __forceinline__ uint4 pack8(float4 a, float4 b){
    union { uint4 u; bf16 h[8]; } r;
    r.h[0]=f2bf(a.x); r.h[1]=f2bf(a.y); r.h[2]=f2bf(a.z); r.h[3]=f2bf(a.w);
    r.h[4]=f2bf(b.x); r.h[5]=f2bf(b.y); r.h[6]=f2bf(b.z); r.h[7]=f2bf(b.w);
    return r.u;
}

// async global->LDS, 16B/lane; lds must be the WAVE-UNIFORM base (deposit = base + lane*16)
__device__ __forceinline__ void glds16(void* lds, const void* g){
    __builtin_amdgcn_global_load_lds(
        (__attribute__((address_space(1))) void*)(size_t)g,
        (__attribute__((address_space(3))) void*)lds,
        16, 0, 0);
}

// ---- weight convert fp32 -> bf16, 8 el/thread -----------------------------------------
__global__ __launch_bounds__(256)
void conv_w(const float* __restrict__ src, bf16* __restrict__ dst){
    const size_t i = ((size_t)blockIdx.x * 256 + threadIdx.x) * 8;
    float4 a = *(const float4*)(src + i);
    float4 b = *(const float4*)(src + i + 4);
    *(uint4*)(dst + i) = pack8(a, b);
}

// ---- 4 D*D weights in one launch (2048 blocks each) -----------------------------------
__global__ __launch_bounds__(256)
void conv_w4(const float* __restrict__ s0, const float* __restrict__ s1,
             const float* __restrict__ s2, const float* __restrict__ s3,
             bf16* __restrict__ dst){
    const int id = blockIdx.x >> 11;
    const float* src = (id == 0) ? s0 : (id == 1) ? s1 : (id == 2) ? s2 : s3;
    const size_t i = ((size_t)(blockIdx.x & 2047) * 256 + threadIdx.x) * 8;
    float4 a = *(const float4*)(src + i);
    float4 b = *(const float4*)(src + i + 4);
    *(uint4*)(dst + (size_t)id * Dc * Dc + i) = pack8(a, b);
}

// ---- dst[i] = bias[i % D] + src[i]  (fp32, 8 el/thread) -------------------------------
__global__ __launch_bounds__(256)
void init_add(float* __restrict__ dst, const float* __restrict__ bias,
              const float* __restrict__ src){
    const size_t i = ((size_t)blockIdx.x * 256 + threadIdx.x) * 8;
    const int col = (int)(i & (Dc - 1));
    float4 a = *(const float4*)(src + i);
    float4 b = *(const float4*)(src + i + 4);
    float4 ba = *(const float4*)(bias + col);
    float4 bb = *(const float4*)(bias + col + 4);
    a.x += ba.x; a.y += ba.y; a.z += ba.z; a.w += ba.w;
    b.x += bb.x; b.y += bb.y; b.z += bb.z; b.w += bb.w;
    *(float4*)(dst + i) = a;
    *(float4*)(dst + i + 4) = b;
}

// ---- LayerNorm: one block per row, D=2048, 256 thr x 8 el; INF32: input dtype ---------
template<int INF32>
__global__ __launch_bounds__(256)
void ln_kernel(const void* __restrict__ x, const float* __restrict__ w,
               const float* __restrict__ b, bf16* __restrict__ y)
{
    const int row = blockIdx.x;
    const int t = threadIdx.x;
    float f[8], s = 0.f, s2 = 0.f;
    if (INF32) {
        const float* xr = (const float*)x + (size_t)row * Dc + t * 8;
        float4 a = *(const float4*)xr, c = *(const float4*)(xr + 4);
        f[0]=a.x; f[1]=a.y; f[2]=a.z; f[3]=a.w; f[4]=c.x; f[5]=c.y; f[6]=c.z; f[7]=c.w;
    } else {
        union { uint4 u; bf16 h[8]; } ld;
        ld.u = *(const uint4*)((const bf16*)x + (size_t)row * Dc + t * 8);
#pragma unroll
        for (int j = 0; j < 8; ++j) f[j] = bf2f(ld.h[j]);
    }
#pragma unroll
    for (int j = 0; j < 8; ++j) { s += f[j]; s2 += f[j] * f[j]; }
#pragma unroll
    for (int off = 32; off; off >>= 1) { s += __shfl_xor(s, off); s2 += __shfl_xor(s2, off); }
    __shared__ float red[8];
    const int wave = t >> 6, lane = t & 63;
    if (lane == 0) { red[wave] = s; red[4 + wave] = s2; }
    __syncthreads();
    s  = red[0] + red[1] + red[2] + red[3];
    s2 = red[4] + red[5] + red[6] + red[7];
    const float mean = s * (1.0f / Dc);
    const float var  = s2 * (1.0f / Dc) - mean * mean;
    const float rs   = rsqrtf(var + 1e-5f);
    union { uint4 u; bf16 h[8]; } st;
#pragma unroll
    for (int j = 0; j < 8; ++j) {
        const int col = t * 8 + j;
        st.h[j] = f2bf((f[j] - mean) * rs * w[col] + b[col]);
    }
    *(uint4*)&y[(size_t)row * Dc + t * 8] = st.u;
}

// =======================================================================================
// GEMM C[M,N] = epi(A[M,K] @ W[N,K]^T + bias) -- 256x256 tile, BK=64, 8 waves (2Mx4N),
// 8-phase schedule, 2-K-TILE LOOKAHEAD with counted vmcnt(6) (T3+T4), setprio (T5),
// XCD swizzle (T1), rotation-swizzled LDS (conflict-free), glds16 width-16 staging.
// EPI: 1 *scale, 2 exact GELU, 3 +residual, 4 fused-QKV, 5 atomic fp32 (no bias)
//
// Read pattern per tile: B rows are read by fixed waves (wnp) in ph1(ks0)+ph2(ks1) --
// BOTH B halves are live through ph2. A-mh0 read ph1+ph2; A-mh1 read ph3+ph4
// (bv0/bv1 registers carry B through ph3/ph4). Earliest safe same-buf staging: ph3.
//
// Stage schedule (buf b = t&1), intra-phase stage/read regions disjoint, every same-buf
// overwrite separated from the region's last read by a barrier:
//   ph1(t): stage A-mh1(t+1) -> buf b^1 (region last read ph4(t-1))   [waited ph4(t)]
//   ph2(t): no stage
//   ph3(t): stage A-mh0(t+2) + B-h0(t+2) -> buf b (last read ph2(t);
//           ph3 reads only A-mh1 -- disjoint)                          [waited ph4(t+1)]
//   ph4(t): stage B-h1(t+2) -> buf b (last read ph2(t); ph4 reads A-mh1); vmcnt(6)
// Ledger at ph4(t): 6 leftover (t+1: A-mh0,B-h0,B-h1) + 2(ph1) + 4(ph3) + 2(ph4) = 14;
// vmcnt(6) waits ALL t+1 halves, keeps t+2's 3 halves in flight (N = 2 loads x 3 = 6).
// Prologue: t0 all 4 halves + t1 {B-h0, A-mh0, B-h1}; vmcnt(6); barrier.
// Tail: ph4(NT-2) drains vmcnt(0); tile NT-1 stages nothing.  NT even for all launches.
// =======================================================================================

#define BAR()   __builtin_amdgcn_s_barrier()
#define LGKM0() asm volatile("s_waitcnt lgkmcnt(0)" ::: "memory")
#define VMW6()  asm volatile("s_waitcnt vmcnt(6)" ::: "memory")
#define VMW0()  asm volatile("s_waitcnt vmcnt(0)" ::: "memory")
#define SCB0()  __builtin_amdgcn_sched_barrier(0)
#define PRIO(x) __builtin_amdgcn_s_setprio(x)

template<int EPI, int RESF32, int OUTF32>
__global__ __launch_bounds__(512, 2)
void gemm_bt(const bf16* __restrict__ A, const bf16* __restrict__ W,
             const float* __restrict__ bias, const float* __restrict__ bias2,
             const float* __restrict__ bias3, const void* __restrict__ res,
             void* __restrict__ C, int M, int N, int K, float scale)
{
    __shared__ __align__(16) char lds[131072];   // 128 KiB: 2 x (A 32K + B 32K)

    // T1: XCD-aware block swizzle (all grids have nwg % 8 == 0)
    const int nwgx = gridDim.x;
    const int nwg  = nwgx * gridDim.y;
    int bid = blockIdx.y * nwgx + blockIdx.x;
    bid = (bid & 7) * (nwg >> 3) + (bid >> 3);
    const int tile_n = (bid % nwgx) * 256;
    const int tile_m = (bid / nwgx) * 256;

    const int t = threadIdx.x;
    const int wave = t >> 6, lane = t & 63, quad = lane >> 4, l16 = lane & 15;
    const int wmp = wave >> 2, wnp = wave & 3;          // 2 M-waves x 4 N-waves
    const int Klen = K / gridDim.z, kbeg = blockIdx.z * Klen;
    const int NT = Klen >> 6;

    // ---- staging constants: each wave stages LDS rows wave*16 .. wave*16+15 ----------
    const int g8  = lane & 7;
    const int lr0 = wave * 16 + (lane >> 3);
    const int lr1 = lr0 + 8;
    const int c0 = (g8 - lr0) & 7, c1 = (g8 - lr1) & 7; // global k-chunk for this granule
    const size_t aof0 = (size_t)(tile_m + (lr0 >> 6) * 128 + (lr0 & 63)) * K + kbeg + c0 * 8;
    const size_t aof1 = (size_t)(tile_m + (lr1 >> 6) * 128 + (lr1 & 63)) * K + kbeg + c1 * 8;
    const size_t bof0 = (size_t)(tile_n + lr0) * K + kbeg + c0 * 8;
    const size_t bof1 = (size_t)(tile_n + lr1) * K + kbeg + c1 * 8;
    const int ls0 = wave * 2048, ls1 = wave * 2048 + 1024;   // wave-uniform LDS bases

    // ---- read constants ---------------------------------------------------------------
    const int ard = (wmp * 64 + l16) * 128;             // A row base within region
    const int brd = 32768 + (wnp * 64 + l16) * 128;     // B row base within buf
    const int gq0 = ((quad + l16) & 7) * 16;            // ks0 granule byte; ks1 = gq0^64

    floatx4 acc[8][4] = {};
    short8 av[4], bv0[4], bv1[4];

#define STAGE_A(_b, _mh, _kt) do { \
    glds16(lds + (_b) * 65536 + (_mh) * 16384 + ls0, \
           A + aof0 + (size_t)((_mh) * 64) * K + (_kt) * 64); \
    glds16(lds + (_b) * 65536 + (_mh) * 16384 + ls1, \
           A + aof1 + (size_t)((_mh) * 64) * K + (_kt) * 64); \
} while (0)

#define STAGE_B(_b, _h, _kt) do { \
    glds16(lds + (_b) * 65536 + 32768 + (_h) * 16384 + ls0, \
           W + bof0 + (size_t)((_h) * 128) * K + (_kt) * 64); \
    glds16(lds + (_b) * 65536 + 32768 + (_h) * 16384 + ls1, \
           W + bof1 + (size_t)((_h) * 128) * K + (_kt) * 64); \
} while (0)

#define LDA4(_b, _mh, _ks) do { \
    const char* _p = lds + (_b) * 65536 + (_mh) * 16384 + ard + (gq0 ^ ((_ks) * 64)); \
    av[0] = *(const short8*)(_p);        av[1] = *(const short8*)(_p + 2048); \
    av[2] = *(const short8*)(_p + 4096); av[3] = *(const short8*)(_p + 6144); \
} while (0)

#define LDB4(_b, _ks, _arr) do { \
    const char* _p = lds + (_b) * 65536 + brd + (gq0 ^ ((_ks) * 64)); \
    _arr[0] = *(const short8*)(_p);        _arr[1] = *(const short8*)(_p + 2048); \
    _arr[2] = *(const short8*)(_p + 4096); _arr[3] = *(const short8*)(_p + 6144); \
} while (0)

#define MFB(_mh, _bv) do { \
    _Pragma("unroll") \
    for (int _mi = 0; _mi < 4; ++_mi) { \
        _Pragma("unroll") \
        for (int _ni = 0; _ni < 4; ++_ni) \
            acc[(_mh) * 4 + _mi][_ni] = __builtin_amdgcn_mfma_f32_16x16x32_bf16( \
                av[_mi], _bv[_ni], acc[(_mh) * 4 + _mi][_ni], 0, 0, 0); \
    } \
} while (0)

#define TILE(_bb, _tt) do { \
    /* ph1: (mh0,ks0); stage A-mh1(t+1) into other buf (region dead since ph4(t-1)) */ \
    LDA4(_bb, 0, 0); LDB4(_bb, 0, bv0); \
    if ((_tt) + 1 < NT) STAGE_A((_bb) ^ 1, 1, (_tt) + 1); \
    BAR(); LGKM0(); SCB0(); PRIO(1); MFB(0, bv0); PRIO(0); BAR(); \
    /* ph2: (mh0,ks1); no stage (A-mh0 and both B halves still being read) */ \
    LDA4(_bb, 0, 1); LDB4(_bb, 1, bv1); \
    BAR(); LGKM0(); SCB0(); PRIO(1); MFB(0, bv1); PRIO(0); BAR(); \
    /* ph3: (mh1,ks0); stage A-mh0(t+2) + B-h0(t+2) (both dead after ph2's barrier; \
       ph3 reads only A-mh1 -- disjoint regions) */ \
    LDA4(_bb, 1, 0); \
    if ((_tt) + 2 < NT) { STAGE_A(_bb, 0, (_tt) + 2); STAGE_B(_bb, 0, (_tt) + 2); } \
    BAR(); LGKM0(); SCB0(); PRIO(1); MFB(1, bv0); PRIO(0); BAR(); \
    /* ph4: (mh1,ks1); stage B-h1(t+2) (dead after ph2; ph4 reads A-mh1); vmcnt(6) */ \
    LDA4(_bb, 1, 1); \
    if ((_tt) + 2 < NT) STAGE_B(_bb, 1, (_tt) + 2); \
    BAR(); LGKM0(); SCB0(); PRIO(1); MFB(1, bv1); PRIO(0); \
    if ((_tt) + 2 < NT)      { VMW6(); } \
    else if ((_tt) + 1 < NT) { VMW0(); } \
    BAR(); \
} while (0)

    // ---- prologue: t0 fully + t1 {B-h0, A-mh0, B-h1}; A-mh1(t1) comes at ph1(t0) ------
    STAGE_A(0, 0, 0); STAGE_A(0, 1, 0);
    STAGE_B(0, 0, 0); STAGE_B(0, 1, 0);
    STAGE_B(1, 0, 1); STAGE_A(1, 0, 1); STAGE_B(1, 1, 1);
    VMW6();
    BAR();

    for (int tt = 0; tt < NT; tt += 2) {
        TILE(0, tt);
        TILE(1, tt + 1);
    }

#undef TILE
#undef MFB
#undef LDB4
#undef LDA4
#undef STAGE_B
#undef STAGE_A

    // ---- epilogue ---------------------------------------------------------------------
#pragma unroll
    for (int mi = 0; mi < 8; ++mi) {
        const int row0 = tile_m + wmp * 128 + mi * 16 + quad * 4;
#pragma unroll
        for (int ni = 0; ni < 4; ++ni) {
            const int col = tile_n + wnp * 64 + ni * 16 + l16;
            float bv = 0.f, sc = 1.f;
            if (EPI == 4) {
                if (col < 2048)      { bv = bias[col];         sc = scale; }
                else if (col < 4096) { bv = bias2[col - 2048]; }
                else                 { bv = bias3[col - 4096]; }
            } else if (EPI != 5) {
                bv = bias[col];
            }
#pragma unroll
            for (int r = 0; r < 4; ++r) {
                const size_t idx = (size_t)(row0 + r) * N + col;
                float v = acc[mi][ni][r];
                if (EPI == 5) { atomicAdd(&((float*)C)[idx], v); continue; }
                v += bv;
                if (EPI == 1) v *= scale;
                if (EPI == 4) v *= sc;
                if (EPI == 2) v = 0.5f * v * (1.0f + erff(v * 0.70710678118f));
                if (EPI == 3) v += RESF32 ? ((const float*)res)[idx] : bf2f(((const bf16*)res)[idx]);
                if (OUTF32) ((float*)C)[idx] = v;
                else        ((bf16*)C)[idx] = f2bf(v);
            }
        }
    }
}

// ---- Flash attention v2 (unchanged) ---------------------------------------------------
__global__ __launch_bounds__(256)
void flash_attn(const bf16* __restrict__ QKV, const float* __restrict__ mask,
                bf16* __restrict__ O)
{
    __shared__ __align__(16) bf16 Ks[4 * 64 * 32];
    __shared__ __align__(16) bf16 Vt[128 * 72];
    __shared__ __align__(16) bf16 Ps[4][16 * 72];
    const int bh = blockIdx.y, b = bh >> 4, h = bh & 15;
    const int t = threadIdx.x, w = t >> 6, lane = t & 63, quad = lane >> 4, l16 = lane & 15;
    const int qbase = blockIdx.x * 64 + w * 16;
    const size_t rowb = (size_t)b * Sc;
    const bf16* Kp = QKV + 2048 + (size_t)h * HDc;
    const bf16* Vp = QKV + 4096 + (size_t)h * HDc;

    short8 qf[4];
    {
        const bf16* qp = QKV + (rowb + qbase + l16) * QKVLD + (size_t)h * HDc + quad * 8;
#pragma unroll
        for (int kc = 0; kc < 4; ++kc) qf[kc] = *(const short8*)(qp + kc * 32);
    }
    float m_i[4], l_i[4];
    floatx4 Oacc[8] = {};
#pragma unroll
    for (int r = 0; r < 4; ++r) { m_i[r] = -1e30f; l_i[r] = 0.f; }

    const int p2 = t & 31, dg = t >> 5;

    for (int kt = 0; kt < Sc; kt += 64) {
        __syncthreads();
#pragma unroll
        for (int u = 0; u < 4; ++u) {
            const int row = u * 16 + (lane >> 2);
            glds16((char*)Ks + w * 4096 + u * 1024,
                   Kp + (rowb + kt + row) * QKVLD + w * 32 + (lane & 3) * 8);
        }
        {
            union { uint4 u4; unsigned short s[8]; } va[2][2];
#pragma unroll
            for (int kk = 0; kk < 2; ++kk) {
                const bf16* vp = Vp + (rowb + kt + 2 * p2 + kk) * QKVLD + dg * 16;
                va[kk][0].u4 = *(const uint4*)vp;
                va[kk][1].u4 = *(const uint4*)(vp + 8);
            }
            unsigned* VtW = (unsigned*)Vt;
#pragma unroll
            for (int j = 0; j < 16; ++j) {
                const unsigned word = (unsigned)va[0][j >> 3].s[j & 7]
                                    | ((unsigned)va[1][j >> 3].s[j & 7] << 16);
                VtW[(dg * 16 + j) * 36 + p2] = word;
            }
        }
        __syncthreads();

        floatx4 sacc[4] = {};
#pragma unroll
        for (int kc = 0; kc < 4; ++kc)
#pragma unroll
            for (int sub = 0; sub < 4; ++sub) {
                short8 kf = *(const short8*)&Ks[kc * 2048 + (sub * 16 + l16) * 32 + quad * 8];
                sacc[sub] = __builtin_amdgcn_mfma_f32_16x16x32_bf16(qf[kc], kf, sacc[sub], 0, 0, 0);
            }
#pragma unroll
        for (int sub = 0; sub < 4; ++sub) {
            const float mv = mask[b * Sc + kt + sub * 16 + l16];
            const float madd = (mv < 0.5f) ? -3.0e38f : 0.f;
#pragma unroll
            for (int r = 0; r < 4; ++r) sacc[sub][r] += madd;
        }
        float p[4][4], alpha[4];
#pragma unroll
        for (int r = 0; r < 4; ++r) {
            float mx = fmaxf(fmaxf(sacc[0][r], sacc[1][r]), fmaxf(sacc[2][r], sacc[3][r]));
#pragma unroll
            for (int off = 8; off; off >>= 1) mx = fmaxf(mx, __shfl_xor(mx, off));
            const float mnew = fmaxf(m_i[r], mx);
            alpha[r] = exp2f(m_i[r] - mnew);
            float ps = 0.f;
#pragma unroll
            for (int sub = 0; sub < 4; ++sub) { p[sub][r] = exp2f(sacc[sub][r] - mnew); ps += p[sub][r]; }
#pragma unroll
            for (int off = 8; off; off >>= 1) ps += __shfl_xor(ps, off);
            l_i[r] = l_i[r] * alpha[r] + ps;
            m_i[r] = mnew;
        }
#pragma unroll
        for (int nsub = 0; nsub < 8; ++nsub)
#pragma unroll
            for (int r = 0; r < 4; ++r) Oacc[nsub][r] *= alpha[r];

        bf16* Pw = Ps[w];
#pragma unroll
        for (int sub = 0; sub < 4; ++sub)
#pragma unroll
            for (int r = 0; r < 4; ++r)
                Pw[(quad * 4 + r) * 72 + sub * 16 + l16] = f2bf(p[sub][r]);
        const short8 pf0 = *(const short8*)&Pw[l16 * 72 + quad * 8];
        const short8 pf1 = *(const short8*)&Pw[l16 * 72 + 32 + quad * 8];
#pragma unroll
        for (int nsub = 0; nsub < 8; ++nsub) {
            const short8 vf0 = *(const short8*)&Vt[(nsub * 16 + l16) * 72 + quad * 8];
            const short8 vf1 = *(const short8*)&Vt[(nsub * 16 + l16) * 72 + 32 + quad * 8];
            Oacc[nsub] = __builtin_amdgcn_mfma_f32_16x16x32_bf16(pf0, vf0, Oacc[nsub], 0, 0, 0);
            Oacc[nsub] = __builtin_amdgcn_mfma_f32_16x16x32_bf16(pf1, vf1, Oacc[nsub], 0, 0, 0);
        }
    }

#pragma unroll
    for (int r = 0; r < 4; ++r) {
        const float inv = 1.f / l_i[r];
        bf16* orow = O + (rowb + qbase + quad * 4 + r) * Dc + (size_t)h * HDc;
#pragma unroll
        for (int nsub = 0; nsub < 8; ++nsub)
            orow[nsub * 16 + l16] = f2bf(Oacc[nsub][r] * inv);
    }
}

// ---------------------------------- launcher ------------------------------------------
extern "C" void kernel_launch(void* const* d_in, const int* in_sizes, int n_in,
                              void* d_out, int out_size, void* d_ws, size_t ws_size,
                              hipStream_t stream)
{
    const float* hidden = (const float*)d_in[1];
    const float* amask  = (const float*)d_in[2];
    const float* Wq = (const float*)d_in[4];  const float* bq = (const float*)d_in[5];
    const float* Wk = (const float*)d_in[6];  const float* bk = (const float*)d_in[7];
    const float* Wv = (const float*)d_in[8];  const float* bv = (const float*)d_in[9];
    const float* Wo = (const float*)d_in[10]; const float* bo = (const float*)d_in[11];
    const float* ln1w = (const float*)d_in[12]; const float* ln1b = (const float*)d_in[13];
    const float* ln2w = (const float*)d_in[14]; const float* ln2b = (const float*)d_in[15];
    const float* W1 = (const float*)d_in[16]; const float* b1 = (const float*)d_in[17];
    const float* W2 = (const float*)d_in[18]; const float* b2 = (const float*)d_in[19];

    const size_t UE = 8ull * 1024 * 1024;     // elements per 16 MB bf16 unit
    const size_t WE = 4ull * 1024 * 1024;     // elements per D*D weight
    bf16*  U = (bf16*)d_ws;
    bf16*  qkv   = U;                         // U0-U2 (48 MB) [4096][6144]
    bf16*  wbuf  = U + 4 * UE;                // U4-U5 (32 MB): Wq|Wk|Wv|Wo, then W1, then W2
    bf16*  x_ln  = U + 6 * UE;                // U6 (dead after QKV gemm)
    float* hid2f = (float*)(U + 6 * UE);      // U6-U7 fp32 32 MB (overlays x_ln)
    bf16*  ffn1  = U;                         // U0-U3 (64 MB; qkv dead)
    bf16*  attn  = (bf16*)d_out;              // d_out[0:16MB)
    bf16*  y_ln  = (bf16*)d_out + UE;         // d_out[16:32MB)
    float* outf  = (float*)d_out;

    const float qscale = 0.08838834764831845f * 1.4426950408889634f; // HD^-0.5 * log2e
    const dim3 gQKV(QKVLD / 256, Bc * Sc / 256, 1);  // (24,16)
    const dim3 gWo (Dc / 256,    Bc * Sc / 256, 2);  // (8,16,2) split-K
    const dim3 gF1 (Ic / 256,    Bc * Sc / 256, 1);  // (32,16)
    const dim3 gF2 (Dc / 256,    Bc * Sc / 256, 2);  // (8,16,2) split-K

    conv_w4<<<8192, 256, 0, stream>>>(Wq, Wk, Wv, Wo, wbuf);
    ln_kernel<1><<<Bc * Sc, 256, 0, stream>>>(hidden, ln1w, ln1b, x_ln);
    gemm_bt<4,0,0><<<gQKV, 512, 0, stream>>>(x_ln, wbuf, bq, bk, bv, nullptr, qkv,
                                             Bc * Sc, QKVLD, Dc, qscale);
    flash_attn<<<dim3(Sc / 64, Bc * Hc), 256, 0, stream>>>(qkv, amask, attn);
    init_add<<<4096, 256, 0, stream>>>(hid2f, bo, hidden);              // hid2f = bo + hidden
    gemm_bt<5,0,1><<<gWo, 512, 0, stream>>>(attn, wbuf + 3 * WE, nullptr, nullptr, nullptr,
                                            nullptr, hid2f, Bc * Sc, Dc, Dc, 0.f);
    ln_kernel<1><<<Bc * Sc, 256, 0, stream>>>(hid2f, ln2w, ln2b, y_ln);
    conv_w<<<8192, 256, 0, stream>>>(W1, wbuf);
    gemm_bt<2,0,0><<<gF1, 512, 0, stream>>>(y_ln, wbuf, b1, nullptr, nullptr, nullptr, ffn1,
                                            Bc * Sc, Ic, Dc, 0.f);
    init_add<<<4096, 256, 0, stream>>>(outf, b2, hid2f);                // d_out = b2 + hid2f
    conv_w<<<8192, 256, 0, stream>>>(W2, wbuf);
    gemm_bt<5,0,1><<<gF2, 512, 0, stream>>>(ffn1, wbuf, nullptr, nullptr, nullptr,
                                            nullptr, outf, Bc * Sc, Dc, Ic, 0.f);
}

// Round 5
// 948.265 us; speedup vs baseline: 1.1183x; 1.1183x over previous
//
#include <hip/hip_runtime.h>
#include <hip/hip_bf16.h>
#include <math.h>

typedef __hip_bfloat16 bf16;
typedef __attribute__((ext_vector_type(8))) short short8;
typedef __attribute__((ext_vector_type(4))) float floatx4;

constexpr int Bc = 4, Sc = 1024, Dc = 2048, Hc = 16, HDc = 128, Ic = 8192;
constexpr int QKVLD = 3 * Dc;  // 6144

__device__ __forceinline__ float bf2f(bf16 x){ return __bfloat162float(x); }
__device__ __forceinline__ bf16 f2bf(float x){ return __float2bfloat16(x); }

__device__ __forceinline__ uint4 pack8(float4 a, float4 b){
    union { uint4 u; bf16 h[8]; } r;
    r.h[0]=f2bf(a.x); r.h[1]=f2bf(a.y); r.h[2]=f2bf(a.z); r.h[3]=f2bf(a.w);
    r.h[4]=f2bf(b.x); r.h[5]=f2bf(b.y); r.h[6]=f2bf(b.z); r.h[7]=f2bf(b.w);
    return r.u;
}

// async global->LDS, 16B/lane; lds must be the WAVE-UNIFORM base (deposit = base + lane*16)
__device__ __forceinline__ void glds16(void* lds, const void* g){
    __builtin_amdgcn_global_load_lds(
        (__attribute__((address_space(1))) void*)(size_t)g,
        (__attribute__((address_space(3))) void*)lds,
        16, 0, 0);
}

// ---- weight convert fp32 -> bf16, 8 el/thread -----------------------------------------
__global__ __launch_bounds__(256)
void conv_w(const float* __restrict__ src, bf16* __restrict__ dst){
    const size_t i = ((size_t)blockIdx.x * 256 + threadIdx.x) * 8;
    float4 a = *(const float4*)(src + i);
    float4 b = *(const float4*)(src + i + 4);
    *(uint4*)(dst + i) = pack8(a, b);
}

// ---- 4 D*D weights in one launch (2048 blocks each) -----------------------------------
__global__ __launch_bounds__(256)
void conv_w4(const float* __restrict__ s0, const float* __restrict__ s1,
             const float* __restrict__ s2, const float* __restrict__ s3,
             bf16* __restrict__ dst){
    const int id = blockIdx.x >> 11;
    const float* src = (id == 0) ? s0 : (id == 1) ? s1 : (id == 2) ? s2 : s3;
    const size_t i = ((size_t)(blockIdx.x & 2047) * 256 + threadIdx.x) * 8;
    float4 a = *(const float4*)(src + i);
    float4 b = *(const float4*)(src + i + 4);
    *(uint4*)(dst + (size_t)id * Dc * Dc + i) = pack8(a, b);
}

// ---- dst[i] = bias[i % D] + src[i]  (fp32, 8 el/thread) -------------------------------
__global__ __launch_bounds__(256)
void init_add(float* __restrict__ dst, const float* __restrict__ bias,
              const float* __restrict__ src){
    const size_t i = ((size_t)blockIdx.x * 256 + threadIdx.x) * 8;
    const int col = (int)(i & (Dc - 1));
    float4 a = *(const float4*)(src + i);
    float4 b = *(const float4*)(src + i + 4);
    float4 ba = *(const float4*)(bias + col);
    float4 bb = *(const float4*)(bias + col + 4);
    a.x += ba.x; a.y += ba.y; a.z += ba.z; a.w += ba.w;
    b.x += bb.x; b.y += bb.y; b.z += bb.z; b.w += bb.w;
    *(float4*)(dst + i) = a;
    *(float4*)(dst + i + 4) = b;
}

// ---- LayerNorm: one block per row, D=2048, 256 thr x 8 el; INF32: input dtype ---------
template<int INF32>
__global__ __launch_bounds__(256)
void ln_kernel(const void* __restrict__ x, const float* __restrict__ w,
               const float* __restrict__ b, bf16* __restrict__ y)
{
    const int row = blockIdx.x;
    const int t = threadIdx.x;
    float f[8], s = 0.f, s2 = 0.f;
    if (INF32) {
        const float* xr = (const float*)x + (size_t)row * Dc + t * 8;
        float4 a = *(const float4*)xr, c = *(const float4*)(xr + 4);
        f[0]=a.x; f[1]=a.y; f[2]=a.z; f[3]=a.w; f[4]=c.x; f[5]=c.y; f[6]=c.z; f[7]=c.w;
    } else {
        union { uint4 u; bf16 h[8]; } ld;
        ld.u = *(const uint4*)((const bf16*)x + (size_t)row * Dc + t * 8);
#pragma unroll
        for (int j = 0; j < 8; ++j) f[j] = bf2f(ld.h[j]);
    }
#pragma unroll
    for (int j = 0; j < 8; ++j) { s += f[j]; s2 += f[j] * f[j]; }
#pragma unroll
    for (int off = 32; off; off >>= 1) { s += __shfl_xor(s, off); s2 += __shfl_xor(s2, off); }
    __shared__ float red[8];
    const int wave = t >> 6, lane = t & 63;
    if (lane == 0) { red[wave] = s; red[4 + wave] = s2; }
    __syncthreads();
    s  = red[0] + red[1] + red[2] + red[3];
    s2 = red[4] + red[5] + red[6] + red[7];
    const float mean = s * (1.0f / Dc);
    const float var  = s2 * (1.0f / Dc) - mean * mean;
    const float rs   = rsqrtf(var + 1e-5f);
    union { uint4 u; bf16 h[8]; } st;
#pragma unroll
    for (int j = 0; j < 8; ++j) {
        const int col = t * 8 + j;
        st.h[j] = f2bf((f[j] - mean) * rs * w[col] + b[col]);
    }
    *(uint4*)&y[(size_t)row * Dc + t * 8] = st.u;
}

// =======================================================================================
// GEMM C[M,N] = epi(A[M,K] @ W[N,K]^T + bias) -- 256x256 tile, BK=64, 8 waves (2Mx4N),
// 8-phase schedule with counted vmcnt (T3+T4), setprio (T5), XCD swizzle (T1),
// rotation-swizzled LDS (conflict-free), global_load_lds width-16 staging.
// EPI: 1 *scale, 2 exact GELU, 3 +residual, 4 fused-QKV, 5 atomic fp32 (no bias)
// split-K via blockIdx.z (EPI=5 accumulates atomically into pre-initialized fp32 C).
//
// *** ROUND-2 MEASURED-BEST SCHEDULE (FFN1 175us / MfmaUtil 34.5%). Round-4's deeper
// *** lookahead (uniform staging + vmcnt(6)) REGRESSED to 262us despite more latency
// *** slack -- do not "improve" this ledger on theory again; A/B measured it.
// Only delta vs round 2: within each phase, STAGE (global_load_lds) issues BEFORE the
// ds_reads (T3 recipe). Stage/read regions are disjoint per phase -> order-safe.
//
// Stage schedule per tile t (buf b = t&1), liveness verified:
//   ph1 (mh0,ks0): stage A-mh1(t+1) + B-h0(t+1) -> buf b^1 (regions last read in t-1,
//                  >=1 barrier ago)
//   ph2 (mh0,ks1): stage B-h1(t+1) -> buf b^1 (last read ph2(t-1))
//   ph3 (mh1,ks0): stage A-mh0(t+2) -> buf b (last read ph2(t), barrier between;
//                  ph3 reads only A-mh1 -- disjoint)
//   ph4 (mh1,ks1): no stage; s_waitcnt vmcnt(2) keeps A-mh0(t+2) in flight, waits all
//                  8 loads of tile t+1. Tail: drain to 0.  NT even for all launches.
// =======================================================================================

#define BAR()   __builtin_amdgcn_s_barrier()
#define LGKM0() asm volatile("s_waitcnt lgkmcnt(0)" ::: "memory")
#define VMW2()  asm volatile("s_waitcnt vmcnt(2)" ::: "memory")
#define VMW0()  asm volatile("s_waitcnt vmcnt(0)" ::: "memory")
#define SCB0()  __builtin_amdgcn_sched_barrier(0)
#define PRIO(x) __builtin_amdgcn_s_setprio(x)

template<int EPI, int RESF32, int OUTF32>
__global__ __launch_bounds__(512, 2)
void gemm_bt(const bf16* __restrict__ A, const bf16* __restrict__ W,
             const float* __restrict__ bias, const float* __restrict__ bias2,
             const float* __restrict__ bias3, const void* __restrict__ res,
             void* __restrict__ C, int M, int N, int K, float scale)
{
    __shared__ __align__(16) char lds[131072];   // 128 KiB: 2 x (A 32K + B 32K)

    // T1: XCD-aware block swizzle (all grids have nwg % 8 == 0)
    const int nwgx = gridDim.x;
    const int nwg  = nwgx * gridDim.y;
    int bid = blockIdx.y * nwgx + blockIdx.x;
    bid = (bid & 7) * (nwg >> 3) + (bid >> 3);
    const int tile_n = (bid % nwgx) * 256;
    const int tile_m = (bid / nwgx) * 256;

    const int t = threadIdx.x;
    const int wave = t >> 6, lane = t & 63, quad = lane >> 4, l16 = lane & 15;
    const int wmp = wave >> 2, wnp = wave & 3;          // 2 M-waves x 4 N-waves
    const int Klen = K / gridDim.z, kbeg = blockIdx.z * Klen;
    const int NT = Klen >> 6;

    // ---- staging constants: each wave stages LDS rows wave*16 .. wave*16+15 ----------
    const int g8  = lane & 7;
    const int lr0 = wave * 16 + (lane >> 3);
    const int lr1 = lr0 + 8;
    const int c0 = (g8 - lr0) & 7, c1 = (g8 - lr1) & 7; // global k-chunk for this granule
    const size_t aof0 = (size_t)(tile_m + (lr0 >> 6) * 128 + (lr0 & 63)) * K + kbeg + c0 * 8;
    const size_t aof1 = (size_t)(tile_m + (lr1 >> 6) * 128 + (lr1 & 63)) * K + kbeg + c1 * 8;
    const size_t bof0 = (size_t)(tile_n + lr0) * K + kbeg + c0 * 8;
    const size_t bof1 = (size_t)(tile_n + lr1) * K + kbeg + c1 * 8;
    const int ls0 = wave * 2048, ls1 = wave * 2048 + 1024;   // wave-uniform LDS bases

    // ---- read constants ---------------------------------------------------------------
    const int ard = (wmp * 64 + l16) * 128;             // A row base within region
    const int brd = 32768 + (wnp * 64 + l16) * 128;     // B row base within buf
    const int gq0 = ((quad + l16) & 7) * 16;            // ks0 granule byte; ks1 = gq0^64

    floatx4 acc[8][4] = {};
    short8 av[4], bv0[4], bv1[4];

#define STAGE_A(_b, _mh, _kt) do { \
    glds16(lds + (_b) * 65536 + (_mh) * 16384 + ls0, \
           A + aof0 + (size_t)((_mh) * 64) * K + (_kt) * 64); \
    glds16(lds + (_b) * 65536 + (_mh) * 16384 + ls1, \
           A + aof1 + (size_t)((_mh) * 64) * K + (_kt) * 64); \
} while (0)

#define STAGE_B(_b, _h, _kt) do { \
    glds16(lds + (_b) * 65536 + 32768 + (_h) * 16384 + ls0, \
           W + bof0 + (size_t)((_h) * 128) * K + (_kt) * 64); \
    glds16(lds + (_b) * 65536 + 32768 + (_h) * 16384 + ls1, \
           W + bof1 + (size_t)((_h) * 128) * K + (_kt) * 64); \
} while (0)

#define LDA4(_b, _mh, _ks) do { \
    const char* _p = lds + (_b) * 65536 + (_mh) * 16384 + ard + (gq0 ^ ((_ks) * 64)); \
    av[0] = *(const short8*)(_p);        av[1] = *(const short8*)(_p + 2048); \
    av[2] = *(const short8*)(_p + 4096); av[3] = *(const short8*)(_p + 6144); \
} while (0)

#define LDB4(_b, _ks, _arr) do { \
    const char* _p = lds + (_b) * 65536 + brd + (gq0 ^ ((_ks) * 64)); \
    _arr[0] = *(const short8*)(_p);        _arr[1] = *(const short8*)(_p + 2048); \
    _arr[2] = *(const short8*)(_p + 4096); _arr[3] = *(const short8*)(_p + 6144); \
} while (0)

#define MFB(_mh, _bv) do { \
    _Pragma("unroll") \
    for (int _mi = 0; _mi < 4; ++_mi) { \
        _Pragma("unroll") \
        for (int _ni = 0; _ni < 4; ++_ni) \
            acc[(_mh) * 4 + _mi][_ni] = __builtin_amdgcn_mfma_f32_16x16x32_bf16( \
                av[_mi], _bv[_ni], acc[(_mh) * 4 + _mi][_ni], 0, 0, 0); \
    } \
} while (0)

#define TILE(_bb, _tt) do { \
    /* ph1: (mh0,ks0); stage A-mh1(t+1)+B-h0(t+1) into other buf (dead since t-1) */ \
    if ((_tt) + 1 < NT) { STAGE_A((_bb) ^ 1, 1, (_tt) + 1); STAGE_B((_bb) ^ 1, 0, (_tt) + 1); } \
    LDA4(_bb, 0, 0); LDB4(_bb, 0, bv0); \
    BAR(); LGKM0(); SCB0(); PRIO(1); MFB(0, bv0); PRIO(0); BAR(); \
    /* ph2: (mh0,ks1); stage B-h1(t+1) into other buf (last read ph2(t-1)) */ \
    if ((_tt) + 1 < NT) STAGE_B((_bb) ^ 1, 1, (_tt) + 1); \
    LDA4(_bb, 0, 1); LDB4(_bb, 1, bv1); \
    BAR(); LGKM0(); SCB0(); PRIO(1); MFB(0, bv1); PRIO(0); BAR(); \
    /* ph3: (mh1,ks0); stage A-mh0(t+2) into this buf (dead after ph2's barrier; \
       ph3 reads only A-mh1 -- disjoint) */ \
    if ((_tt) + 2 < NT) STAGE_A(_bb, 0, (_tt) + 2); \
    LDA4(_bb, 1, 0); \
    BAR(); LGKM0(); SCB0(); PRIO(1); MFB(1, bv0); PRIO(0); BAR(); \
    /* ph4: (mh1,ks1); no stage; counted vmcnt BEFORE the barrier */ \
    LDA4(_bb, 1, 1); \
    BAR(); LGKM0(); SCB0(); PRIO(1); MFB(1, bv1); PRIO(0); \
    if ((_tt) + 2 < NT)      { VMW2(); } \
    else if ((_tt) + 1 < NT) { VMW0(); } \
    BAR(); \
} while (0)

    // ---- prologue: tile0 complete + A1 H0; keep A1H0 in flight ------------------------
    STAGE_A(0, 0, 0); STAGE_A(0, 1, 0);
    STAGE_B(0, 0, 0); STAGE_B(0, 1, 0);
    STAGE_A(1, 0, 1);
    VMW2();
    BAR();

    for (int tt = 0; tt < NT; tt += 2) {
        TILE(0, tt);
        TILE(1, tt + 1);
    }

#undef TILE
#undef MFB
#undef LDB4
#undef LDA4
#undef STAGE_B
#undef STAGE_A

    // ---- epilogue ---------------------------------------------------------------------
#pragma unroll
    for (int mi = 0; mi < 8; ++mi) {
        const int row0 = tile_m + wmp * 128 + mi * 16 + quad * 4;
#pragma unroll
        for (int ni = 0; ni < 4; ++ni) {
            const int col = tile_n + wnp * 64 + ni * 16 + l16;
            float bv = 0.f, sc = 1.f;
            if (EPI == 4) {
                if (col < 2048)      { bv = bias[col];         sc = scale; }
                else if (col < 4096) { bv = bias2[col - 2048]; }
                else                 { bv = bias3[col - 4096]; }
            } else if (EPI != 5) {
                bv = bias[col];
            }
#pragma unroll
            for (int r = 0; r < 4; ++r) {
                const size_t idx = (size_t)(row0 + r) * N + col;
                float v = acc[mi][ni][r];
                if (EPI == 5) { atomicAdd(&((float*)C)[idx], v); continue; }
                v += bv;
                if (EPI == 1) v *= scale;
                if (EPI == 4) v *= sc;
                if (EPI == 2) v = 0.5f * v * (1.0f + erff(v * 0.70710678118f));
                if (EPI == 3) v += RESF32 ? ((const float*)res)[idx] : bf2f(((const bf16*)res)[idx]);
                if (OUTF32) ((float*)C)[idx] = v;
                else        ((bf16*)C)[idx] = f2bf(v);
            }
        }
    }
}

// ---- Flash attention v2 (unchanged) ---------------------------------------------------
__global__ __launch_bounds__(256)
void flash_attn(const bf16* __restrict__ QKV, const float* __restrict__ mask,
                bf16* __restrict__ O)
{
    __shared__ __align__(16) bf16 Ks[4 * 64 * 32];
    __shared__ __align__(16) bf16 Vt[128 * 72];
    __shared__ __align__(16) bf16 Ps[4][16 * 72];
    const int bh = blockIdx.y, b = bh >> 4, h = bh & 15;
    const int t = threadIdx.x, w = t >> 6, lane = t & 63, quad = lane >> 4, l16 = lane & 15;
    const int qbase = blockIdx.x * 64 + w * 16;
    const size_t rowb = (size_t)b * Sc;
    const bf16* Kp = QKV + 2048 + (size_t)h * HDc;
    const bf16* Vp = QKV + 4096 + (size_t)h * HDc;

    short8 qf[4];
    {
        const bf16* qp = QKV + (rowb + qbase + l16) * QKVLD + (size_t)h * HDc + quad * 8;
#pragma unroll
        for (int kc = 0; kc < 4; ++kc) qf[kc] = *(const short8*)(qp + kc * 32);
    }
    float m_i[4], l_i[4];
    floatx4 Oacc[8] = {};
#pragma unroll
    for (int r = 0; r < 4; ++r) { m_i[r] = -1e30f; l_i[r] = 0.f; }

    const int p2 = t & 31, dg = t >> 5;

    for (int kt = 0; kt < Sc; kt += 64) {
        __syncthreads();
#pragma unroll
        for (int u = 0; u < 4; ++u) {
            const int row = u * 16 + (lane >> 2);
            glds16((char*)Ks + w * 4096 + u * 1024,
                   Kp + (rowb + kt + row) * QKVLD + w * 32 + (lane & 3) * 8);
        }
        {
            union { uint4 u4; unsigned short s[8]; } va[2][2];
#pragma unroll
            for (int kk = 0; kk < 2; ++kk) {
                const bf16* vp = Vp + (rowb + kt + 2 * p2 + kk) * QKVLD + dg * 16;
                va[kk][0].u4 = *(const uint4*)vp;
                va[kk][1].u4 = *(const uint4*)(vp + 8);
            }
            unsigned* VtW = (unsigned*)Vt;
#pragma unroll
            for (int j = 0; j < 16; ++j) {
                const unsigned word = (unsigned)va[0][j >> 3].s[j & 7]
                                    | ((unsigned)va[1][j >> 3].s[j & 7] << 16);
                VtW[(dg * 16 + j) * 36 + p2] = word;
            }
        }
        __syncthreads();

        floatx4 sacc[4] = {};
#pragma unroll
        for (int kc = 0; kc < 4; ++kc)
#pragma unroll
            for (int sub = 0; sub < 4; ++sub) {
                short8 kf = *(const short8*)&Ks[kc * 2048 + (sub * 16 + l16) * 32 + quad * 8];
                sacc[sub] = __builtin_amdgcn_mfma_f32_16x16x32_bf16(qf[kc], kf, sacc[sub], 0, 0, 0);
            }
#pragma unroll
        for (int sub = 0; sub < 4; ++sub) {
            const float mv = mask[b * Sc + kt + sub * 16 + l16];
            const float madd = (mv < 0.5f) ? -3.0e38f : 0.f;
#pragma unroll
            for (int r = 0; r < 4; ++r) sacc[sub][r] += madd;
        }
        float p[4][4], alpha[4];
#pragma unroll
        for (int r = 0; r < 4; ++r) {
            float mx = fmaxf(fmaxf(sacc[0][r], sacc[1][r]), fmaxf(sacc[2][r], sacc[3][r]));
#pragma unroll
            for (int off = 8; off; off >>= 1) mx = fmaxf(mx, __shfl_xor(mx, off));
            const float mnew = fmaxf(m_i[r], mx);
            alpha[r] = exp2f(m_i[r] - mnew);
            float ps = 0.f;
#pragma unroll
            for (int sub = 0; sub < 4; ++sub) { p[sub][r] = exp2f(sacc[sub][r] - mnew); ps += p[sub][r]; }
#pragma unroll
            for (int off = 8; off; off >>= 1) ps += __shfl_xor(ps, off);
            l_i[r] = l_i[r] * alpha[r] + ps;
            m_i[r] = mnew;
        }
#pragma unroll
        for (int nsub = 0; nsub < 8; ++nsub)
#pragma unroll
            for (int r = 0; r < 4; ++r) Oacc[nsub][r] *= alpha[r];

        bf16* Pw = Ps[w];
#pragma unroll
        for (int sub = 0; sub < 4; ++sub)
#pragma unroll
            for (int r = 0; r < 4; ++r)
                Pw[(quad * 4 + r) * 72 + sub * 16 + l16] = f2bf(p[sub][r]);
        const short8 pf0 = *(const short8*)&Pw[l16 * 72 + quad * 8];
        const short8 pf1 = *(const short8*)&Pw[l16 * 72 + 32 + quad * 8];
#pragma unroll
        for (int nsub = 0; nsub < 8; ++nsub) {
            const short8 vf0 = *(const short8*)&Vt[(nsub * 16 + l16) * 72 + quad * 8];
            const short8 vf1 = *(const short8*)&Vt[(nsub * 16 + l16) * 72 + 32 + quad * 8];
            Oacc[nsub] = __builtin_amdgcn_mfma_f32_16x16x32_bf16(pf0, vf0, Oacc[nsub], 0, 0, 0);
            Oacc[nsub] = __builtin_amdgcn_mfma_f32_16x16x32_bf16(pf1, vf1, Oacc[nsub], 0, 0, 0);
        }
    }

#pragma unroll
    for (int r = 0; r < 4; ++r) {
        const float inv = 1.f / l_i[r];
        bf16* orow = O + (rowb + qbase + quad * 4 + r) * Dc + (size_t)h * HDc;
#pragma unroll
        for (int nsub = 0; nsub < 8; ++nsub)
            orow[nsub * 16 + l16] = f2bf(Oacc[nsub][r] * inv);
    }
}

// ---------------------------------- launcher ------------------------------------------
extern "C" void kernel_launch(void* const* d_in, const int* in_sizes, int n_in,
                              void* d_out, int out_size, void* d_ws, size_t ws_size,
                              hipStream_t stream)
{
    const float* hidden = (const float*)d_in[1];
    const float* amask  = (const float*)d_in[2];
    const float* Wq = (const float*)d_in[4];  const float* bq = (const float*)d_in[5];
    const float* Wk = (const float*)d_in[6];  const float* bk = (const float*)d_in[7];
    const float* Wv = (const float*)d_in[8];  const float* bv = (const float*)d_in[9];
    const float* Wo = (const float*)d_in[10]; const float* bo = (const float*)d_in[11];
    const float* ln1w = (const float*)d_in[12]; const float* ln1b = (const float*)d_in[13];
    const float* ln2w = (const float*)d_in[14]; const float* ln2b = (const float*)d_in[15];
    const float* W1 = (const float*)d_in[16]; const float* b1 = (const float*)d_in[17];
    const float* W2 = (const float*)d_in[18]; const float* b2 = (const float*)d_in[19];

    const size_t UE = 8ull * 1024 * 1024;     // elements per 16 MB bf16 unit
    const size_t WE = 4ull * 1024 * 1024;     // elements per D*D weight
    bf16*  U = (bf16*)d_ws;
    bf16*  qkv   = U;                         // U0-U2 (48 MB) [4096][6144]
    bf16*  wbuf  = U + 4 * UE;                // U4-U5 (32 MB): Wq|Wk|Wv|Wo, then W1, then W2
    bf16*  x_ln  = U + 6 * UE;                // U6 (dead after QKV gemm)
    float* hid2f = (float*)(U + 6 * UE);      // U6-U7 fp32 32 MB (overlays x_ln)
    bf16*  ffn1  = U;                         // U0-U3 (64 MB; qkv dead)
    bf16*  attn  = (bf16*)d_out;              // d_out[0:16MB)
    bf16*  y_ln  = (bf16*)d_out + UE;         // d_out[16:32MB)
    float* outf  = (float*)d_out;

    const float qscale = 0.08838834764831845f * 1.4426950408889634f; // HD^-0.5 * log2e
    const dim3 gQKV(QKVLD / 256, Bc * Sc / 256, 1);  // (24,16)
    const dim3 gWo (Dc / 256,    Bc * Sc / 256, 2);  // (8,16,2) split-K
    const dim3 gF1 (Ic / 256,    Bc * Sc / 256, 1);  // (32,16)
    const dim3 gF2 (Dc / 256,    Bc * Sc / 256, 2);  // (8,16,2) split-K

    conv_w4<<<8192, 256, 0, stream>>>(Wq, Wk, Wv, Wo, wbuf);
    ln_kernel<1><<<Bc * Sc, 256, 0, stream>>>(hidden, ln1w, ln1b, x_ln);
    gemm_bt<4,0,0><<<gQKV, 512, 0, stream>>>(x_ln, wbuf, bq, bk, bv, nullptr, qkv,
                                             Bc * Sc, QKVLD, Dc, qscale);
    flash_attn<<<dim3(Sc / 64, Bc * Hc), 256, 0, stream>>>(qkv, amask, attn);
    init_add<<<4096, 256, 0, stream>>>(hid2f, bo, hidden);              // hid2f = bo + hidden
    gemm_bt<5,0,1><<<gWo, 512, 0, stream>>>(attn, wbuf + 3 * WE, nullptr, nullptr, nullptr,
                                            nullptr, hid2f, Bc * Sc, Dc, Dc, 0.f);
    ln_kernel<1><<<Bc * Sc, 256, 0, stream>>>(hid2f, ln2w, ln2b, y_ln);
    conv_w<<<8192, 256, 0, stream>>>(W1, wbuf);
    gemm_bt<2,0,0><<<gF1, 512, 0, stream>>>(y_ln, wbuf, b1, nullptr, nullptr, nullptr, ffn1,
                                            Bc * Sc, Ic, Dc, 0.f);
    init_add<<<4096, 256, 0, stream>>>(outf, b2, hid2f);                // d_out = b2 + hid2f
    conv_w<<<8192, 256, 0, stream>>>(W2, wbuf);
    gemm_bt<5,0,1><<<gF2, 512, 0, stream>>>(ffn1, wbuf, nullptr, nullptr, nullptr,
                                            nullptr, outf, Bc * Sc, Dc, Ic, 0.f);
}

// Round 7
// 878.830 us; speedup vs baseline: 1.2067x; 1.0790x over previous
//
#include <hip/hip_runtime.h>
#include <hip/hip_bf16.h>
#include <math.h>

typedef __hip_bfloat16 bf16;
typedef __attribute__((ext_vector_type(8))) short short8;
typedef __attribute__((ext_vector_type(4))) float floatx4;

constexpr int Bc = 4, Sc = 1024, Dc = 2048, Hc = 16, HDc = 128, Ic = 8192;
constexpr int QKVLD = 3 * Dc;  // 6144

__device__ __forceinline__ float bf2f(bf16 x){ return __bfloat162float(x); }
__device__ __forceinline__ bf16 f2bf(float x){ return __float2bfloat16(x); }

__device__ __forceinline__ uint4 pack8(float4 a, float4 b){
    union { uint4 u; bf16 h[8]; } r;
    r.h[0]=f2bf(a.x); r.h[1]=f2bf(a.y); r.h[2]=f2bf(a.z); r.h[3]=f2bf(a.w);
    r.h[4]=f2bf(b.x); r.h[5]=f2bf(b.y); r.h[6]=f2bf(b.z); r.h[7]=f2bf(b.w);
    return r.u;
}

// async global->LDS, 16B/lane; lds must be the WAVE-UNIFORM base (deposit = base + lane*16)
__device__ __forceinline__ void glds16(void* lds, const void* g){
    __builtin_amdgcn_global_load_lds(
        (__attribute__((address_space(1))) void*)(size_t)g,
        (__attribute__((address_space(3))) void*)lds,
        16, 0, 0);
}

// ---- weight convert fp32 -> bf16, 8 el/thread -----------------------------------------
__global__ __launch_bounds__(256)
void conv_w(const float* __restrict__ src, bf16* __restrict__ dst){
    const size_t i = ((size_t)blockIdx.x * 256 + threadIdx.x) * 8;
    float4 a = *(const float4*)(src + i);
    float4 b = *(const float4*)(src + i + 4);
    *(uint4*)(dst + i) = pack8(a, b);
}

// ---- 4 D*D weights in one launch (2048 blocks each) -----------------------------------
__global__ __launch_bounds__(256)
void conv_w4(const float* __restrict__ s0, const float* __restrict__ s1,
             const float* __restrict__ s2, const float* __restrict__ s3,
             bf16* __restrict__ dst){
    const int id = blockIdx.x >> 11;
    const float* src = (id == 0) ? s0 : (id == 1) ? s1 : (id == 2) ? s2 : s3;
    const size_t i = ((size_t)(blockIdx.x & 2047) * 256 + threadIdx.x) * 8;
    float4 a = *(const float4*)(src + i);
    float4 b = *(const float4*)(src + i + 4);
    *(uint4*)(dst + (size_t)id * Dc * Dc + i) = pack8(a, b);
}

// ---- LayerNorm: one block per row, D=2048, 256 thr x 8 el; INF32: input dtype ---------
template<int INF32>
__global__ __launch_bounds__(256)
void ln_kernel(const void* __restrict__ x, const float* __restrict__ w,
               const float* __restrict__ b, bf16* __restrict__ y)
{
    const int row = blockIdx.x;
    const int t = threadIdx.x;
    float f[8], s = 0.f, s2 = 0.f;
    if (INF32) {
        const float* xr = (const float*)x + (size_t)row * Dc + t * 8;
        float4 a = *(const float4*)xr, c = *(const float4*)(xr + 4);
        f[0]=a.x; f[1]=a.y; f[2]=a.z; f[3]=a.w; f[4]=c.x; f[5]=c.y; f[6]=c.z; f[7]=c.w;
    } else {
        union { uint4 u; bf16 h[8]; } ld;
        ld.u = *(const uint4*)((const bf16*)x + (size_t)row * Dc + t * 8);
#pragma unroll
        for (int j = 0; j < 8; ++j) f[j] = bf2f(ld.h[j]);
    }
#pragma unroll
    for (int j = 0; j < 8; ++j) { s += f[j]; s2 += f[j] * f[j]; }
#pragma unroll
    for (int off = 32; off; off >>= 1) { s += __shfl_xor(s, off); s2 += __shfl_xor(s2, off); }
    __shared__ float red[8];
    const int wave = t >> 6, lane = t & 63;
    if (lane == 0) { red[wave] = s; red[4 + wave] = s2; }
    __syncthreads();
    s  = red[0] + red[1] + red[2] + red[3];
    s2 = red[4] + red[5] + red[6] + red[7];
    const float mean = s * (1.0f / Dc);
    const float var  = s2 * (1.0f / Dc) - mean * mean;
    const float rs   = rsqrtf(var + 1e-5f);
    union { uint4 u; bf16 h[8]; } st;
#pragma unroll
    for (int j = 0; j < 8; ++j) {
        const int col = t * 8 + j;
        st.h[j] = f2bf((f[j] - mean) * rs * w[col] + b[col]);
    }
    *(uint4*)&y[(size_t)row * Dc + t * 8] = st.u;
}

#define BAR()   __builtin_amdgcn_s_barrier()
#define LGKM0() asm volatile("s_waitcnt lgkmcnt(0)" ::: "memory")
#define VMW2()  asm volatile("s_waitcnt vmcnt(2)" ::: "memory")
#define VMW1()  asm volatile("s_waitcnt vmcnt(1)" ::: "memory")
#define VMW0()  asm volatile("s_waitcnt vmcnt(0)" ::: "memory")
#define SCB0()  __builtin_amdgcn_sched_barrier(0)
#define PRIO(x) __builtin_amdgcn_s_setprio(x)

// =======================================================================================
// GEMM 256x256 tile, BK=64, 8 waves (2Mx4N) -- ROUND-2 MEASURED-BEST schedule (FFN1
// 175us / MfmaUtil 33%). Schedule axis is triple-measured; do not alter on theory.
// Used for FFN1 only (M=4096, N=8192 -> 512 blocks = 2/CU balanced).
// EPI: 1 *scale, 2 exact GELU, 3 +residual, 4 fused-QKV, 5 atomic fp32 (no bias)
// =======================================================================================
template<int EPI, int RESF32, int OUTF32>
__global__ __launch_bounds__(512, 2)
void gemm_bt(const bf16* __restrict__ A, const bf16* __restrict__ W,
             const float* __restrict__ bias, const float* __restrict__ bias2,
             const float* __restrict__ bias3, const void* __restrict__ res,
             void* __restrict__ C, int M, int N, int K, float scale)
{
    __shared__ __align__(16) char lds[131072];   // 128 KiB: 2 x (A 32K + B 32K)

    const int nwgx = gridDim.x;
    const int nwg  = nwgx * gridDim.y;
    int bid = blockIdx.y * nwgx + blockIdx.x;
    bid = (bid & 7) * (nwg >> 3) + (bid >> 3);
    const int tile_n = (bid % nwgx) * 256;
    const int tile_m = (bid / nwgx) * 256;

    const int t = threadIdx.x;
    const int wave = t >> 6, lane = t & 63, quad = lane >> 4, l16 = lane & 15;
    const int wmp = wave >> 2, wnp = wave & 3;          // 2 M-waves x 4 N-waves
    const int Klen = K / gridDim.z, kbeg = blockIdx.z * Klen;
    const int NT = Klen >> 6;

    const int g8  = lane & 7;
    const int lr0 = wave * 16 + (lane >> 3);
    const int lr1 = lr0 + 8;
    const int c0 = (g8 - lr0) & 7, c1 = (g8 - lr1) & 7;
    const size_t aof0 = (size_t)(tile_m + (lr0 >> 6) * 128 + (lr0 & 63)) * K + kbeg + c0 * 8;
    const size_t aof1 = (size_t)(tile_m + (lr1 >> 6) * 128 + (lr1 & 63)) * K + kbeg + c1 * 8;
    const size_t bof0 = (size_t)(tile_n + lr0) * K + kbeg + c0 * 8;
    const size_t bof1 = (size_t)(tile_n + lr1) * K + kbeg + c1 * 8;
    const int ls0 = wave * 2048, ls1 = wave * 2048 + 1024;

    const int ard = (wmp * 64 + l16) * 128;
    const int brd = 32768 + (wnp * 64 + l16) * 128;
    const int gq0 = ((quad + l16) & 7) * 16;

    floatx4 acc[8][4] = {};
    short8 av[4], bv0[4], bv1[4];

#define STAGE_A(_b, _mh, _kt) do { \
    glds16(lds + (_b) * 65536 + (_mh) * 16384 + ls0, \
           A + aof0 + (size_t)((_mh) * 64) * K + (_kt) * 64); \
    glds16(lds + (_b) * 65536 + (_mh) * 16384 + ls1, \
           A + aof1 + (size_t)((_mh) * 64) * K + (_kt) * 64); \
} while (0)

#define STAGE_B(_b, _h, _kt) do { \
    glds16(lds + (_b) * 65536 + 32768 + (_h) * 16384 + ls0, \
           W + bof0 + (size_t)((_h) * 128) * K + (_kt) * 64); \
    glds16(lds + (_b) * 65536 + 32768 + (_h) * 16384 + ls1, \
           W + bof1 + (size_t)((_h) * 128) * K + (_kt) * 64); \
} while (0)

#define LDA4(_b, _mh, _ks) do { \
    const char* _p = lds + (_b) * 65536 + (_mh) * 16384 + ard + (gq0 ^ ((_ks) * 64)); \
    av[0] = *(const short8*)(_p);        av[1] = *(const short8*)(_p + 2048); \
    av[2] = *(const short8*)(_p + 4096); av[3] = *(const short8*)(_p + 6144); \
} while (0)

#define LDB4(_b, _ks, _arr) do { \
    const char* _p = lds + (_b) * 65536 + brd + (gq0 ^ ((_ks) * 64)); \
    _arr[0] = *(const short8*)(_p);        _arr[1] = *(const short8*)(_p + 2048); \
    _arr[2] = *(const short8*)(_p + 4096); _arr[3] = *(const short8*)(_p + 6144); \
} while (0)

#define MFB(_mh, _bv) do { \
    _Pragma("unroll") \
    for (int _mi = 0; _mi < 4; ++_mi) { \
        _Pragma("unroll") \
        for (int _ni = 0; _ni < 4; ++_ni) \
            acc[(_mh) * 4 + _mi][_ni] = __builtin_amdgcn_mfma_f32_16x16x32_bf16( \
                av[_mi], _bv[_ni], acc[(_mh) * 4 + _mi][_ni], 0, 0, 0); \
    } \
} while (0)

#define TILE(_bb, _tt) do { \
    if ((_tt) + 1 < NT) { STAGE_A((_bb) ^ 1, 1, (_tt) + 1); STAGE_B((_bb) ^ 1, 0, (_tt) + 1); } \
    LDA4(_bb, 0, 0); LDB4(_bb, 0, bv0); \
    BAR(); LGKM0(); SCB0(); PRIO(1); MFB(0, bv0); PRIO(0); BAR(); \
    if ((_tt) + 1 < NT) STAGE_B((_bb) ^ 1, 1, (_tt) + 1); \
    LDA4(_bb, 0, 1); LDB4(_bb, 1, bv1); \
    BAR(); LGKM0(); SCB0(); PRIO(1); MFB(0, bv1); PRIO(0); BAR(); \
    if ((_tt) + 2 < NT) STAGE_A(_bb, 0, (_tt) + 2); \
    LDA4(_bb, 1, 0); \
    BAR(); LGKM0(); SCB0(); PRIO(1); MFB(1, bv0); PRIO(0); BAR(); \
    LDA4(_bb, 1, 1); \
    BAR(); LGKM0(); SCB0(); PRIO(1); MFB(1, bv1); PRIO(0); \
    if ((_tt) + 2 < NT)      { VMW2(); } \
    else if ((_tt) + 1 < NT) { VMW0(); } \
    BAR(); \
} while (0)

    STAGE_A(0, 0, 0); STAGE_A(0, 1, 0);
    STAGE_B(0, 0, 0); STAGE_B(0, 1, 0);
    STAGE_A(1, 0, 1);
    VMW2();
    BAR();

    for (int tt = 0; tt < NT; tt += 2) {
        TILE(0, tt);
        TILE(1, tt + 1);
    }

#undef TILE
#undef MFB
#undef LDB4
#undef LDA4
#undef STAGE_B
#undef STAGE_A

#pragma unroll
    for (int mi = 0; mi < 8; ++mi) {
        const int row0 = tile_m + wmp * 128 + mi * 16 + quad * 4;
#pragma unroll
        for (int ni = 0; ni < 4; ++ni) {
            const int col = tile_n + wnp * 64 + ni * 16 + l16;
            float bv = 0.f, sc = 1.f;
            if (EPI == 4) {
                if (col < 2048)      { bv = bias[col];         sc = scale; }
                else if (col < 4096) { bv = bias2[col - 2048]; }
                else                 { bv = bias3[col - 4096]; }
            } else if (EPI != 5) {
                bv = bias[col];
            }
#pragma unroll
            for (int r = 0; r < 4; ++r) {
                const size_t idx = (size_t)(row0 + r) * N + col;
                float v = acc[mi][ni][r];
                if (EPI == 5) { atomicAdd(&((float*)C)[idx], v); continue; }
                v += bv;
                if (EPI == 1) v *= scale;
                if (EPI == 4) v *= sc;
                if (EPI == 2) v = 0.5f * v * (1.0f + erff(v * 0.70710678118f));
                if (EPI == 3) v += RESF32 ? ((const float*)res)[idx] : bf2f(((const bf16*)res)[idx]);
                if (OUTF32) ((float*)C)[idx] = v;
                else        ((bf16*)C)[idx] = f2bf(v);
            }
        }
    }
}

// =======================================================================================
// GEMM 128x256 tile, BK=64, 8 waves (2Mx4N, 64x64/wave) -- same r2 4-phase cadence,
// ledger re-derived for the 6-load tile (audit r6: ledger/liveness/addressing all
// re-verified; no intra-phase stage/read overlap; same-buf stage only at ph3 after
// the region's last read + barrier).
// QKV (768 blk = 3/CU), Wo and FFN2 (256 blk = 1/CU, EPI=3 fuses bias+residual ->
// no split-K atomics, no init_add pass).
// LDS buf b at b*49152: A 16KB (half mh at mh*8192, 64 rows x 128B), B 32KB at +16384
// (row r of 256 at r*128). Rotation swizzle: granule g of row r holds k-chunk (g-r)&7.
// Stage schedule per tile t (buf b = t&1):
//   ph1: A-mh1(t+1)->b^1 [1 load];  ph2: B-h0(t+1)+B-h1(t+1)->b^1 [4];
//   ph3: A-mh0(t+2)->b [1] (region's last read = ph2(t), barrier between);
//   ph4: vmcnt(1) waits all 6 t+1 loads, keeps A-mh0(t+2).
// MFMA: ph1 ks0 x nsub01, ph2 ks0 x nsub23, ph3 ks1 x nsub01, ph4 ks1 x nsub23.
// =======================================================================================
template<int EPI, int RESF32, int OUTF32>
__global__ __launch_bounds__(512, 2)
void gemm_bt_h(const bf16* __restrict__ A, const bf16* __restrict__ W,
               const float* __restrict__ bias, const float* __restrict__ bias2,
               const float* __restrict__ bias3, const void* __restrict__ res,
               void* __restrict__ C, int M, int N, int K, float scale)
{
    __shared__ __align__(16) char lds[98304];   // 96 KiB: 2 x (A 16K + B 32K)

    const int nwgx = gridDim.x;
    const int nwg  = nwgx * gridDim.y;
    int bid = blockIdx.y * nwgx + blockIdx.x;
    bid = (bid & 7) * (nwg >> 3) + (bid >> 3);
    const int tile_n = (bid % nwgx) * 256;
    const int tile_m = (bid / nwgx) * 128;

    const int t = threadIdx.x;
    const int wave = t >> 6, lane = t & 63, quad = lane >> 4, l16 = lane & 15;
    const int wmp = wave >> 2, wnp = wave & 3;          // 2 M-waves x 4 N-waves
    const int NT = K >> 6;

    // staging: each wave covers 8 rows x 8 granules per glds16 sweep (1KB)
    const int arow = wave * 8 + (lane >> 3);            // 0..63 within a 64-row region
    const int ca   = ((lane & 7) - arow) & 7;           // global k-chunk for this granule
    const size_t aofh = (size_t)(tile_m + arow) * K + ca * 8;
    const size_t bofh = (size_t)(tile_n + arow) * K + ca * 8;
    const int lsw = wave * 1024;                        // wave-uniform LDS base

    const int ard = wmp * 8192 + l16 * 128;             // own A half
    const int brd = 16384 + (wnp * 64 + l16) * 128;     // own B 64-col slice
    const int gq0 = ((quad + l16) & 7) * 16;            // ks0 granule byte; ks1 = ^64

    floatx4 acc[4][4] = {};
    short8 av0[4], av1[4], bv0[4], bv1[4];

#define STAGEH_A(_b, _mh, _kt) \
    glds16(lds + (_b) * 49152 + (_mh) * 8192 + lsw, \
           A + aofh + (size_t)((_mh) * 64) * K + (_kt) * 64)

#define STAGEH_B(_b, _h, _kt) do { \
    glds16(lds + (_b) * 49152 + 16384 + (_h) * 16384 + lsw, \
           W + bofh + (size_t)((_h) * 128) * K + (_kt) * 64); \
    glds16(lds + (_b) * 49152 + 16384 + (_h) * 16384 + 8192 + lsw, \
           W + bofh + (size_t)((_h) * 128 + 64) * K + (_kt) * 64); \
} while (0)

#define LDAH(_b, _ks, _arr) do { \
    const char* _p = lds + (_b) * 49152 + ard + (gq0 ^ ((_ks) * 64)); \
    _arr[0] = *(const short8*)(_p);        _arr[1] = *(const short8*)(_p + 2048); \
    _arr[2] = *(const short8*)(_p + 4096); _arr[3] = *(const short8*)(_p + 6144); \
} while (0)

#define LDBH(_b, _ks, _arr) do { \
    const char* _p = lds + (_b) * 49152 + brd + (gq0 ^ ((_ks) * 64)); \
    _arr[0] = *(const short8*)(_p);        _arr[1] = *(const short8*)(_p + 2048); \
    _arr[2] = *(const short8*)(_p + 4096); _arr[3] = *(const short8*)(_p + 6144); \
} while (0)

#define MF8(_av, _bv, _n0, _n1) do { \
    _Pragma("unroll") \
    for (int _mi = 0; _mi < 4; ++_mi) { \
        acc[_mi][_n0] = __builtin_amdgcn_mfma_f32_16x16x32_bf16(_av[_mi], _bv[_n0], acc[_mi][_n0], 0, 0, 0); \
        acc[_mi][_n1] = __builtin_amdgcn_mfma_f32_16x16x32_bf16(_av[_mi], _bv[_n1], acc[_mi][_n1], 0, 0, 0); \
    } \
} while (0)

#define TILEH(_bb, _tt) do { \
    /* ph1 */ \
    if ((_tt) + 1 < NT) STAGEH_A((_bb) ^ 1, 1, (_tt) + 1); \
    LDAH(_bb, 0, av0); LDBH(_bb, 0, bv0); \
    BAR(); LGKM0(); SCB0(); PRIO(1); MF8(av0, bv0, 0, 1); PRIO(0); BAR(); \
    /* ph2 */ \
    if ((_tt) + 1 < NT) { STAGEH_B((_bb) ^ 1, 0, (_tt) + 1); STAGEH_B((_bb) ^ 1, 1, (_tt) + 1); } \
    LDAH(_bb, 1, av1); LDBH(_bb, 1, bv1); \
    BAR(); LGKM0(); SCB0(); PRIO(1); MF8(av0, bv0, 2, 3); PRIO(0); BAR(); \
    /* ph3: A-mh0(b) last read ph2 (barrier between); ph3 reads no LDS */ \
    if ((_tt) + 2 < NT) STAGEH_A(_bb, 0, (_tt) + 2); \
    BAR(); LGKM0(); SCB0(); PRIO(1); MF8(av1, bv1, 0, 1); PRIO(0); BAR(); \
    /* ph4: counted vmcnt BEFORE the barrier */ \
    BAR(); SCB0(); PRIO(1); MF8(av1, bv1, 2, 3); PRIO(0); \
    if ((_tt) + 2 < NT)      { VMW1(); } \
    else if ((_tt) + 1 < NT) { VMW0(); } \
    BAR(); \
} while (0)

    // prologue: t0 all regions [6 loads] + A-mh0(t1) [1]; vmcnt(1) keeps the newest 1
    STAGEH_A(0, 0, 0); STAGEH_A(0, 1, 0);
    STAGEH_B(0, 0, 0); STAGEH_B(0, 1, 0);
    STAGEH_A(1, 0, 1);
    VMW1();
    BAR();

    for (int tt = 0; tt < NT; tt += 2) {
        TILEH(0, tt);
        TILEH(1, tt + 1);
    }

#undef TILEH
#undef MF8
#undef LDBH
#undef LDAH
#undef STAGEH_B
#undef STAGEH_A

    // epilogue: per wave 64x64 output
#pragma unroll
    for (int mi = 0; mi < 4; ++mi) {
        const int row0 = tile_m + wmp * 64 + mi * 16 + quad * 4;
#pragma unroll
        for (int ni = 0; ni < 4; ++ni) {
            const int col = tile_n + wnp * 64 + ni * 16 + l16;
            float bv = 0.f, sc = 1.f;
            if (EPI == 4) {
                if (col < 2048)      { bv = bias[col];         sc = scale; }
                else if (col < 4096) { bv = bias2[col - 2048]; }
                else                 { bv = bias3[col - 4096]; }
            } else if (EPI != 5) {
                bv = bias[col];
            }
#pragma unroll
            for (int r = 0; r < 4; ++r) {
                const size_t idx = (size_t)(row0 + r) * N + col;
                float v = acc[mi][ni][r];
                if (EPI == 5) { atomicAdd(&((float*)C)[idx], v); continue; }
                v += bv;
                if (EPI == 1) v *= scale;
                if (EPI == 4) v *= sc;
                if (EPI == 2) v = 0.5f * v * (1.0f + erff(v * 0.70710678118f));
                if (EPI == 3) v += RESF32 ? ((const float*)res)[idx] : bf2f(((const bf16*)res)[idx]);
                if (OUTF32) ((float*)C)[idx] = v;
                else        ((bf16*)C)[idx] = f2bf(v);
            }
        }
    }
}

// ---- Flash attention v2 (unchanged) ---------------------------------------------------
__global__ __launch_bounds__(256)
void flash_attn(const bf16* __restrict__ QKV, const float* __restrict__ mask,
                bf16* __restrict__ O)
{
    __shared__ __align__(16) bf16 Ks[4 * 64 * 32];
    __shared__ __align__(16) bf16 Vt[128 * 72];
    __shared__ __align__(16) bf16 Ps[4][16 * 72];
    const int bh = blockIdx.y, b = bh >> 4, h = bh & 15;
    const int t = threadIdx.x, w = t >> 6, lane = t & 63, quad = lane >> 4, l16 = lane & 15;
    const int qbase = blockIdx.x * 64 + w * 16;
    const size_t rowb = (size_t)b * Sc;
    const bf16* Kp = QKV + 2048 + (size_t)h * HDc;
    const bf16* Vp = QKV + 4096 + (size_t)h * HDc;

    short8 qf[4];
    {
        const bf16* qp = QKV + (rowb + qbase + l16) * QKVLD + (size_t)h * HDc + quad * 8;
#pragma unroll
        for (int kc = 0; kc < 4; ++kc) qf[kc] = *(const short8*)(qp + kc * 32);
    }
    float m_i[4], l_i[4];
    floatx4 Oacc[8] = {};
#pragma unroll
    for (int r = 0; r < 4; ++r) { m_i[r] = -1e30f; l_i[r] = 0.f; }

    const int p2 = t & 31, dg = t >> 5;

    for (int kt = 0; kt < Sc; kt += 64) {
        __syncthreads();
#pragma unroll
        for (int u = 0; u < 4; ++u) {
            const int row = u * 16 + (lane >> 2);
            glds16((char*)Ks + w * 4096 + u * 1024,
                   Kp + (rowb + kt + row) * QKVLD + w * 32 + (lane & 3) * 8);
        }
        {
            union { uint4 u4; unsigned short s[8]; } va[2][2];
#pragma unroll
            for (int kk = 0; kk < 2; ++kk) {
                const bf16* vp = Vp + (rowb + kt + 2 * p2 + kk) * QKVLD + dg * 16;
                va[kk][0].u4 = *(const uint4*)vp;
                va[kk][1].u4 = *(const uint4*)(vp + 8);
            }
            unsigned* VtW = (unsigned*)Vt;
#pragma unroll
            for (int j = 0; j < 16; ++j) {
                const unsigned word = (unsigned)va[0][j >> 3].s[j & 7]
                                    | ((unsigned)va[1][j >> 3].s[j & 7] << 16);
                VtW[(dg * 16 + j) * 36 + p2] = word;
            }
        }
        __syncthreads();

        floatx4 sacc[4] = {};
#pragma unroll
        for (int kc = 0; kc < 4; ++kc)
#pragma unroll
            for (int sub = 0; sub < 4; ++sub) {
                short8 kf = *(const short8*)&Ks[kc * 2048 + (sub * 16 + l16) * 32 + quad * 8];
                sacc[sub] = __builtin_amdgcn_mfma_f32_16x16x32_bf16(qf[kc], kf, sacc[sub], 0, 0, 0);
            }
#pragma unroll
        for (int sub = 0; sub < 4; ++sub) {
            const float mv = mask[b * Sc + kt + sub * 16 + l16];
            const float madd = (mv < 0.5f) ? -3.0e38f : 0.f;
#pragma unroll
            for (int r = 0; r < 4; ++r) sacc[sub][r] += madd;
        }
        float p[4][4], alpha[4];
#pragma unroll
        for (int r = 0; r < 4; ++r) {
            float mx = fmaxf(fmaxf(sacc[0][r], sacc[1][r]), fmaxf(sacc[2][r], sacc[3][r]));
#pragma unroll
            for (int off = 8; off; off >>= 1) mx = fmaxf(mx, __shfl_xor(mx, off));
            const float mnew = fmaxf(m_i[r], mx);
            alpha[r] = exp2f(m_i[r] - mnew);
            float ps = 0.f;
#pragma unroll
            for (int sub = 0; sub < 4; ++sub) { p[sub][r] = exp2f(sacc[sub][r] - mnew); ps += p[sub][r]; }
#pragma unroll
            for (int off = 8; off; off >>= 1) ps += __shfl_xor(ps, off);
            l_i[r] = l_i[r] * alpha[r] + ps;
            m_i[r] = mnew;
        }
#pragma unroll
        for (int nsub = 0; nsub < 8; ++nsub)
#pragma unroll
            for (int r = 0; r < 4; ++r) Oacc[nsub][r] *= alpha[r];

        bf16* Pw = Ps[w];
#pragma unroll
        for (int sub = 0; sub < 4; ++sub)
#pragma unroll
            for (int r = 0; r < 4; ++r)
                Pw[(quad * 4 + r) * 72 + sub * 16 + l16] = f2bf(p[sub][r]);
        const short8 pf0 = *(const short8*)&Pw[l16 * 72 + quad * 8];
        const short8 pf1 = *(const short8*)&Pw[l16 * 72 + 32 + quad * 8];
#pragma unroll
        for (int nsub = 0; nsub < 8; ++nsub) {
            const short8 vf0 = *(const short8*)&Vt[(nsub * 16 + l16) * 72 + quad * 8];
            const short8 vf1 = *(const short8*)&Vt[(nsub * 16 + l16) * 72 + 32 + quad * 8];
            Oacc[nsub] = __builtin_amdgcn_mfma_f32_16x16x32_bf16(pf0, vf0, Oacc[nsub], 0, 0, 0);
            Oacc[nsub] = __builtin_amdgcn_mfma_f32_16x16x32_bf16(pf1, vf1, Oacc[nsub], 0, 0, 0);
        }
    }

#pragma unroll
    for (int r = 0; r < 4; ++r) {
        const float inv = 1.f / l_i[r];
        bf16* orow = O + (rowb + qbase + quad * 4 + r) * Dc + (size_t)h * HDc;
#pragma unroll
        for (int nsub = 0; nsub < 8; ++nsub)
            orow[nsub * 16 + l16] = f2bf(Oacc[nsub][r] * inv);
    }
}

// ---------------------------------- launcher ------------------------------------------
extern "C" void kernel_launch(void* const* d_in, const int* in_sizes, int n_in,
                              void* d_out, int out_size, void* d_ws, size_t ws_size,
                              hipStream_t stream)
{
    const float* hidden = (const float*)d_in[1];
    const float* amask  = (const float*)d_in[2];
    const float* Wq = (const float*)d_in[4];  const float* bq = (const float*)d_in[5];
    const float* Wk = (const float*)d_in[6];  const float* bk = (const float*)d_in[7];
    const float* Wv = (const float*)d_in[8];  const float* bv = (const float*)d_in[9];
    const float* Wo = (const float*)d_in[10]; const float* bo = (const float*)d_in[11];
    const float* ln1w = (const float*)d_in[12]; const float* ln1b = (const float*)d_in[13];
    const float* ln2w = (const float*)d_in[14]; const float* ln2b = (const float*)d_in[15];
    const float* W1 = (const float*)d_in[16]; const float* b1 = (const float*)d_in[17];
    const float* W2 = (const float*)d_in[18]; const float* b2 = (const float*)d_in[19];

    const size_t UE = 8ull * 1024 * 1024;     // elements per 16 MB bf16 unit
    const size_t WE = 4ull * 1024 * 1024;     // elements per D*D weight
    bf16*  U = (bf16*)d_ws;
    bf16*  qkv   = U;                         // U0-U2 (48 MB) [4096][6144]
    bf16*  wbuf  = U + 4 * UE;                // U4-U5 (32 MB): Wq|Wk|Wv|Wo, then W1, then W2
    bf16*  x_ln  = U + 6 * UE;                // U6 (dead after QKV gemm)
    float* hid2f = (float*)(U + 6 * UE);      // U6-U7 fp32 32 MB (overlays x_ln)
    bf16*  ffn1  = U;                         // U0-U3 (64 MB; qkv dead)
    bf16*  attn  = (bf16*)d_out;              // d_out[0:16MB)
    bf16*  y_ln  = (bf16*)d_out + UE;         // d_out[16:32MB)
    float* outf  = (float*)d_out;

    const float qscale = 0.08838834764831845f * 1.4426950408889634f; // HD^-0.5 * log2e
    const dim3 gQKV(QKVLD / 256, Bc * Sc / 128, 1);  // (24,32) 768 blk = 3/CU exact
    const dim3 gWo (Dc / 256,    Bc * Sc / 128, 1);  // (8,32)  256 blk = 1/CU exact
    const dim3 gF1 (Ic / 256,    Bc * Sc / 256, 1);  // (32,16) 512 blk = 2/CU exact
    const dim3 gF2 (Dc / 256,    Bc * Sc / 128, 1);  // (8,32)  256 blk = 1/CU exact

    conv_w4<<<8192, 256, 0, stream>>>(Wq, Wk, Wv, Wo, wbuf);
    ln_kernel<1><<<Bc * Sc, 256, 0, stream>>>(hidden, ln1w, ln1b, x_ln);
    // QKV (fused bias + q-scale), balanced 128x256 grid
    gemm_bt_h<4,0,0><<<gQKV, 512, 0, stream>>>(x_ln, wbuf, bq, bk, bv, nullptr, qkv,
                                               Bc * Sc, QKVLD, Dc, qscale);
    flash_attn<<<dim3(Sc / 64, Bc * Hc), 256, 0, stream>>>(qkv, amask, attn);
    // hid2f = attn @ Wo^T + bo + hidden   (fused residual, fp32 out; no atomics)
    gemm_bt_h<3,1,1><<<gWo, 512, 0, stream>>>(attn, wbuf + 3 * WE, bo, nullptr, nullptr,
                                              hidden, hid2f, Bc * Sc, Dc, Dc, 0.f);
    ln_kernel<1><<<Bc * Sc, 256, 0, stream>>>(hid2f, ln2w, ln2b, y_ln);
    conv_w<<<8192, 256, 0, stream>>>(W1, wbuf);
    gemm_bt<2,0,0><<<gF1, 512, 0, stream>>>(y_ln, wbuf, b1, nullptr, nullptr, nullptr, ffn1,
                                            Bc * Sc, Ic, Dc, 0.f);
    conv_w<<<8192, 256, 0, stream>>>(W2, wbuf);
    // d_out = ffn1 @ W2^T + b2 + hid2f   (fused residual, fp32 out; no atomics)
    gemm_bt_h<3,1,1><<<gF2, 512, 0, stream>>>(ffn1, wbuf, b2, nullptr, nullptr,
                                              hid2f, outf, Bc * Sc, Dc, Ic, 0.f);
}

// Round 8
// 866.868 us; speedup vs baseline: 1.2233x; 1.0138x over previous
//
#include <hip/hip_runtime.h>
#include <hip/hip_bf16.h>
#include <math.h>

typedef __hip_bfloat16 bf16;
typedef __attribute__((ext_vector_type(8))) short short8;
typedef __attribute__((ext_vector_type(4))) float floatx4;

constexpr int Bc = 4, Sc = 1024, Dc = 2048, Hc = 16, HDc = 128, Ic = 8192;
constexpr int QKVLD = 3 * Dc;  // 6144

__device__ __forceinline__ float bf2f(bf16 x){ return __bfloat162float(x); }
__device__ __forceinline__ bf16 f2bf(float x){ return __float2bfloat16(x); }

__device__ __forceinline__ uint4 pack8(float4 a, float4 b){
    union { uint4 u; bf16 h[8]; } r;
    r.h[0]=f2bf(a.x); r.h[1]=f2bf(a.y); r.h[2]=f2bf(a.z); r.h[3]=f2bf(a.w);
    r.h[4]=f2bf(b.x); r.h[5]=f2bf(b.y); r.h[6]=f2bf(b.z); r.h[7]=f2bf(b.w);
    return r.u;
}

// async global->LDS, 16B/lane; lds must be the WAVE-UNIFORM base (deposit = base + lane*16)
__device__ __forceinline__ void glds16(void* lds, const void* g){
    __builtin_amdgcn_global_load_lds(
        (__attribute__((address_space(1))) void*)(size_t)g,
        (__attribute__((address_space(3))) void*)lds,
        16, 0, 0);
}

// ---- weight convert fp32 -> bf16, 8 el/thread -----------------------------------------
__global__ __launch_bounds__(256)
void conv_w(const float* __restrict__ src, bf16* __restrict__ dst){
    const size_t i = ((size_t)blockIdx.x * 256 + threadIdx.x) * 8;
    float4 a = *(const float4*)(src + i);
    float4 b = *(const float4*)(src + i + 4);
    *(uint4*)(dst + i) = pack8(a, b);
}

// ---- 4 D*D weights in one launch (2048 blocks each) -----------------------------------
__global__ __launch_bounds__(256)
void conv_w4(const float* __restrict__ s0, const float* __restrict__ s1,
             const float* __restrict__ s2, const float* __restrict__ s3,
             bf16* __restrict__ dst){
    const int id = blockIdx.x >> 11;
    const float* src = (id == 0) ? s0 : (id == 1) ? s1 : (id == 2) ? s2 : s3;
    const size_t i = ((size_t)(blockIdx.x & 2047) * 256 + threadIdx.x) * 8;
    float4 a = *(const float4*)(src + i);
    float4 b = *(const float4*)(src + i + 4);
    *(uint4*)(dst + (size_t)id * Dc * Dc + i) = pack8(a, b);
}

// ---- LayerNorm: one block per row, D=2048, 256 thr x 8 el; INF32: input dtype ---------
template<int INF32>
__global__ __launch_bounds__(256)
void ln_kernel(const void* __restrict__ x, const float* __restrict__ w,
               const float* __restrict__ b, bf16* __restrict__ y)
{
    const int row = blockIdx.x;
    const int t = threadIdx.x;
    float f[8], s = 0.f, s2 = 0.f;
    if (INF32) {
        const float* xr = (const float*)x + (size_t)row * Dc + t * 8;
        float4 a = *(const float4*)xr, c = *(const float4*)(xr + 4);
        f[0]=a.x; f[1]=a.y; f[2]=a.z; f[3]=a.w; f[4]=c.x; f[5]=c.y; f[6]=c.z; f[7]=c.w;
    } else {
        union { uint4 u; bf16 h[8]; } ld;
        ld.u = *(const uint4*)((const bf16*)x + (size_t)row * Dc + t * 8);
#pragma unroll
        for (int j = 0; j < 8; ++j) f[j] = bf2f(ld.h[j]);
    }
#pragma unroll
    for (int j = 0; j < 8; ++j) { s += f[j]; s2 += f[j] * f[j]; }
#pragma unroll
    for (int off = 32; off; off >>= 1) { s += __shfl_xor(s, off); s2 += __shfl_xor(s2, off); }
    __shared__ float red[8];
    const int wave = t >> 6, lane = t & 63;
    if (lane == 0) { red[wave] = s; red[4 + wave] = s2; }
    __syncthreads();
    s  = red[0] + red[1] + red[2] + red[3];
    s2 = red[4] + red[5] + red[6] + red[7];
    const float mean = s * (1.0f / Dc);
    const float var  = s2 * (1.0f / Dc) - mean * mean;
    const float rs   = rsqrtf(var + 1e-5f);
    union { uint4 u; bf16 h[8]; } st;
#pragma unroll
    for (int j = 0; j < 8; ++j) {
        const int col = t * 8 + j;
        st.h[j] = f2bf((f[j] - mean) * rs * w[col] + b[col]);
    }
    *(uint4*)&y[(size_t)row * Dc + t * 8] = st.u;
}

#define BAR()   __builtin_amdgcn_s_barrier()
#define LGKM0() asm volatile("s_waitcnt lgkmcnt(0)" ::: "memory")
#define VMW2()  asm volatile("s_waitcnt vmcnt(2)" ::: "memory")
#define VMW1()  asm volatile("s_waitcnt vmcnt(1)" ::: "memory")
#define VMW0()  asm volatile("s_waitcnt vmcnt(0)" ::: "memory")
#define SCB0()  __builtin_amdgcn_sched_barrier(0)
#define PRIO(x) __builtin_amdgcn_s_setprio(x)

// =======================================================================================
// GEMM 256x256 tile, BK=64, 8 waves (2Mx4N) -- ROUND-2 MEASURED-BEST schedule (FFN1
// 175us / MfmaUtil 33%). Schedule axis is triple-measured; do not alter on theory.
// Used for FFN1 only (M=4096, N=8192 -> 512 blocks = 2/CU balanced).
// EPI: 1 *scale, 2 exact GELU, 3 +residual, 4 fused-QKV, 5 atomic fp32 (no bias)
// =======================================================================================
template<int EPI, int RESF32, int OUTF32>
__global__ __launch_bounds__(512, 2)
void gemm_bt(const bf16* __restrict__ A, const bf16* __restrict__ W,
             const float* __restrict__ bias, const float* __restrict__ bias2,
             const float* __restrict__ bias3, const void* __restrict__ res,
             void* __restrict__ C, int M, int N, int K, float scale)
{
    __shared__ __align__(16) char lds[131072];   // 128 KiB: 2 x (A 32K + B 32K)

    const int nwgx = gridDim.x;
    const int nwg  = nwgx * gridDim.y;
    int bid = blockIdx.y * nwgx + blockIdx.x;
    bid = (bid & 7) * (nwg >> 3) + (bid >> 3);
    const int tile_n = (bid % nwgx) * 256;
    const int tile_m = (bid / nwgx) * 256;

    const int t = threadIdx.x;
    const int wave = t >> 6, lane = t & 63, quad = lane >> 4, l16 = lane & 15;
    const int wmp = wave >> 2, wnp = wave & 3;          // 2 M-waves x 4 N-waves
    const int Klen = K / gridDim.z, kbeg = blockIdx.z * Klen;
    const int NT = Klen >> 6;

    const int g8  = lane & 7;
    const int lr0 = wave * 16 + (lane >> 3);
    const int lr1 = lr0 + 8;
    const int c0 = (g8 - lr0) & 7, c1 = (g8 - lr1) & 7;
    const size_t aof0 = (size_t)(tile_m + (lr0 >> 6) * 128 + (lr0 & 63)) * K + kbeg + c0 * 8;
    const size_t aof1 = (size_t)(tile_m + (lr1 >> 6) * 128 + (lr1 & 63)) * K + kbeg + c1 * 8;
    const size_t bof0 = (size_t)(tile_n + lr0) * K + kbeg + c0 * 8;
    const size_t bof1 = (size_t)(tile_n + lr1) * K + kbeg + c1 * 8;
    const int ls0 = wave * 2048, ls1 = wave * 2048 + 1024;

    const int ard = (wmp * 64 + l16) * 128;
    const int brd = 32768 + (wnp * 64 + l16) * 128;
    const int gq0 = ((quad + l16) & 7) * 16;

    floatx4 acc[8][4] = {};
    short8 av[4], bv0[4], bv1[4];

#define STAGE_A(_b, _mh, _kt) do { \
    glds16(lds + (_b) * 65536 + (_mh) * 16384 + ls0, \
           A + aof0 + (size_t)((_mh) * 64) * K + (_kt) * 64); \
    glds16(lds + (_b) * 65536 + (_mh) * 16384 + ls1, \
           A + aof1 + (size_t)((_mh) * 64) * K + (_kt) * 64); \
} while (0)

#define STAGE_B(_b, _h, _kt) do { \
    glds16(lds + (_b) * 65536 + 32768 + (_h) * 16384 + ls0, \
           W + bof0 + (size_t)((_h) * 128) * K + (_kt) * 64); \
    glds16(lds + (_b) * 65536 + 32768 + (_h) * 16384 + ls1, \
           W + bof1 + (size_t)((_h) * 128) * K + (_kt) * 64); \
} while (0)

#define LDA4(_b, _mh, _ks) do { \
    const char* _p = lds + (_b) * 65536 + (_mh) * 16384 + ard + (gq0 ^ ((_ks) * 64)); \
    av[0] = *(const short8*)(_p);        av[1] = *(const short8*)(_p + 2048); \
    av[2] = *(const short8*)(_p + 4096); av[3] = *(const short8*)(_p + 6144); \
} while (0)

#define LDB4(_b, _ks, _arr) do { \
    const char* _p = lds + (_b) * 65536 + brd + (gq0 ^ ((_ks) * 64)); \
    _arr[0] = *(const short8*)(_p);        _arr[1] = *(const short8*)(_p + 2048); \
    _arr[2] = *(const short8*)(_p + 4096); _arr[3] = *(const short8*)(_p + 6144); \
} while (0)

#define MFB(_mh, _bv) do { \
    _Pragma("unroll") \
    for (int _mi = 0; _mi < 4; ++_mi) { \
        _Pragma("unroll") \
        for (int _ni = 0; _ni < 4; ++_ni) \
            acc[(_mh) * 4 + _mi][_ni] = __builtin_amdgcn_mfma_f32_16x16x32_bf16( \
                av[_mi], _bv[_ni], acc[(_mh) * 4 + _mi][_ni], 0, 0, 0); \
    } \
} while (0)

#define TILE(_bb, _tt) do { \
    if ((_tt) + 1 < NT) { STAGE_A((_bb) ^ 1, 1, (_tt) + 1); STAGE_B((_bb) ^ 1, 0, (_tt) + 1); } \
    LDA4(_bb, 0, 0); LDB4(_bb, 0, bv0); \
    BAR(); LGKM0(); SCB0(); PRIO(1); MFB(0, bv0); PRIO(0); BAR(); \
    if ((_tt) + 1 < NT) STAGE_B((_bb) ^ 1, 1, (_tt) + 1); \
    LDA4(_bb, 0, 1); LDB4(_bb, 1, bv1); \
    BAR(); LGKM0(); SCB0(); PRIO(1); MFB(0, bv1); PRIO(0); BAR(); \
    if ((_tt) + 2 < NT) STAGE_A(_bb, 0, (_tt) + 2); \
    LDA4(_bb, 1, 0); \
    BAR(); LGKM0(); SCB0(); PRIO(1); MFB(1, bv0); PRIO(0); BAR(); \
    LDA4(_bb, 1, 1); \
    BAR(); LGKM0(); SCB0(); PRIO(1); MFB(1, bv1); PRIO(0); \
    if ((_tt) + 2 < NT)      { VMW2(); } \
    else if ((_tt) + 1 < NT) { VMW0(); } \
    BAR(); \
} while (0)

    STAGE_A(0, 0, 0); STAGE_A(0, 1, 0);
    STAGE_B(0, 0, 0); STAGE_B(0, 1, 0);
    STAGE_A(1, 0, 1);
    VMW2();
    BAR();

    for (int tt = 0; tt < NT; tt += 2) {
        TILE(0, tt);
        TILE(1, tt + 1);
    }

#undef TILE
#undef MFB
#undef LDB4
#undef LDA4
#undef STAGE_B
#undef STAGE_A

#pragma unroll
    for (int mi = 0; mi < 8; ++mi) {
        const int row0 = tile_m + wmp * 128 + mi * 16 + quad * 4;
#pragma unroll
        for (int ni = 0; ni < 4; ++ni) {
            const int col = tile_n + wnp * 64 + ni * 16 + l16;
            float bv = 0.f, sc = 1.f;
            if (EPI == 4) {
                if (col < 2048)      { bv = bias[col];         sc = scale; }
                else if (col < 4096) { bv = bias2[col - 2048]; }
                else                 { bv = bias3[col - 4096]; }
            } else if (EPI != 5) {
                bv = bias[col];
            }
#pragma unroll
            for (int r = 0; r < 4; ++r) {
                const size_t idx = (size_t)(row0 + r) * N + col;
                float v = acc[mi][ni][r];
                if (EPI == 5) { atomicAdd(&((float*)C)[idx], v); continue; }
                v += bv;
                if (EPI == 1) v *= scale;
                if (EPI == 4) v *= sc;
                if (EPI == 2) v = 0.5f * v * (1.0f + erff(v * 0.70710678118f));
                if (EPI == 3) v += RESF32 ? ((const float*)res)[idx] : bf2f(((const bf16*)res)[idx]);
                if (OUTF32) ((float*)C)[idx] = v;
                else        ((bf16*)C)[idx] = f2bf(v);
            }
        }
    }
}

// =======================================================================================
// GEMM 128x256 tile, BK=64, 8 waves (2Mx4N, 64x64/wave) -- same r2 4-phase cadence,
// 6-load ledger (verified r6/r7: QKV 768 blk = 3/CU, Wo/FFN2 256 blk = 1/CU, fused
// bias+residual, no atomics).
// =======================================================================================
template<int EPI, int RESF32, int OUTF32>
__global__ __launch_bounds__(512, 2)
void gemm_bt_h(const bf16* __restrict__ A, const bf16* __restrict__ W,
               const float* __restrict__ bias, const float* __restrict__ bias2,
               const float* __restrict__ bias3, const void* __restrict__ res,
               void* __restrict__ C, int M, int N, int K, float scale)
{
    __shared__ __align__(16) char lds[98304];   // 96 KiB: 2 x (A 16K + B 32K)

    const int nwgx = gridDim.x;
    const int nwg  = nwgx * gridDim.y;
    int bid = blockIdx.y * nwgx + blockIdx.x;
    bid = (bid & 7) * (nwg >> 3) + (bid >> 3);
    const int tile_n = (bid % nwgx) * 256;
    const int tile_m = (bid / nwgx) * 128;

    const int t = threadIdx.x;
    const int wave = t >> 6, lane = t & 63, quad = lane >> 4, l16 = lane & 15;
    const int wmp = wave >> 2, wnp = wave & 3;          // 2 M-waves x 4 N-waves
    const int NT = K >> 6;

    // staging: each wave covers 8 rows x 8 granules per glds16 sweep (1KB)
    const int arow = wave * 8 + (lane >> 3);            // 0..63 within a 64-row region
    const int ca   = ((lane & 7) - arow) & 7;           // global k-chunk for this granule
    const size_t aofh = (size_t)(tile_m + arow) * K + ca * 8;
    const size_t bofh = (size_t)(tile_n + arow) * K + ca * 8;
    const int lsw = wave * 1024;                        // wave-uniform LDS base

    const int ard = wmp * 8192 + l16 * 128;             // own A half
    const int brd = 16384 + (wnp * 64 + l16) * 128;     // own B 64-col slice
    const int gq0 = ((quad + l16) & 7) * 16;            // ks0 granule byte; ks1 = ^64

    floatx4 acc[4][4] = {};
    short8 av0[4], av1[4], bv0[4], bv1[4];

#define STAGEH_A(_b, _mh, _kt) \
    glds16(lds + (_b) * 49152 + (_mh) * 8192 + lsw, \
           A + aofh + (size_t)((_mh) * 64) * K + (_kt) * 64)

#define STAGEH_B(_b, _h, _kt) do { \
    glds16(lds + (_b) * 49152 + 16384 + (_h) * 16384 + lsw, \
           W + bofh + (size_t)((_h) * 128) * K + (_kt) * 64); \
    glds16(lds + (_b) * 49152 + 16384 + (_h) * 16384 + 8192 + lsw, \
           W + bofh + (size_t)((_h) * 128 + 64) * K + (_kt) * 64); \
} while (0)

#define LDAH(_b, _ks, _arr) do { \
    const char* _p = lds + (_b) * 49152 + ard + (gq0 ^ ((_ks) * 64)); \
    _arr[0] = *(const short8*)(_p);        _arr[1] = *(const short8*)(_p + 2048); \
    _arr[2] = *(const short8*)(_p + 4096); _arr[3] = *(const short8*)(_p + 6144); \
} while (0)

#define LDBH(_b, _ks, _arr) do { \
    const char* _p = lds + (_b) * 49152 + brd + (gq0 ^ ((_ks) * 64)); \
    _arr[0] = *(const short8*)(_p);        _arr[1] = *(const short8*)(_p + 2048); \
    _arr[2] = *(const short8*)(_p + 4096); _arr[3] = *(const short8*)(_p + 6144); \
} while (0)

#define MF8(_av, _bv, _n0, _n1) do { \
    _Pragma("unroll") \
    for (int _mi = 0; _mi < 4; ++_mi) { \
        acc[_mi][_n0] = __builtin_amdgcn_mfma_f32_16x16x32_bf16(_av[_mi], _bv[_n0], acc[_mi][_n0], 0, 0, 0); \
        acc[_mi][_n1] = __builtin_amdgcn_mfma_f32_16x16x32_bf16(_av[_mi], _bv[_n1], acc[_mi][_n1], 0, 0, 0); \
    } \
} while (0)

#define TILEH(_bb, _tt) do { \
    /* ph1 */ \
    if ((_tt) + 1 < NT) STAGEH_A((_bb) ^ 1, 1, (_tt) + 1); \
    LDAH(_bb, 0, av0); LDBH(_bb, 0, bv0); \
    BAR(); LGKM0(); SCB0(); PRIO(1); MF8(av0, bv0, 0, 1); PRIO(0); BAR(); \
    /* ph2 */ \
    if ((_tt) + 1 < NT) { STAGEH_B((_bb) ^ 1, 0, (_tt) + 1); STAGEH_B((_bb) ^ 1, 1, (_tt) + 1); } \
    LDAH(_bb, 1, av1); LDBH(_bb, 1, bv1); \
    BAR(); LGKM0(); SCB0(); PRIO(1); MF8(av0, bv0, 2, 3); PRIO(0); BAR(); \
    /* ph3: A-mh0(b) last read ph2 (barrier between); ph3 reads no LDS */ \
    if ((_tt) + 2 < NT) STAGEH_A(_bb, 0, (_tt) + 2); \
    BAR(); LGKM0(); SCB0(); PRIO(1); MF8(av1, bv1, 0, 1); PRIO(0); BAR(); \
    /* ph4: counted vmcnt BEFORE the barrier */ \
    BAR(); SCB0(); PRIO(1); MF8(av1, bv1, 2, 3); PRIO(0); \
    if ((_tt) + 2 < NT)      { VMW1(); } \
    else if ((_tt) + 1 < NT) { VMW0(); } \
    BAR(); \
} while (0)

    // prologue: t0 all regions [6 loads] + A-mh0(t1) [1]; vmcnt(1) keeps the newest 1
    STAGEH_A(0, 0, 0); STAGEH_A(0, 1, 0);
    STAGEH_B(0, 0, 0); STAGEH_B(0, 1, 0);
    STAGEH_A(1, 0, 1);
    VMW1();
    BAR();

    for (int tt = 0; tt < NT; tt += 2) {
        TILEH(0, tt);
        TILEH(1, tt + 1);
    }

#undef TILEH
#undef MF8
#undef LDBH
#undef LDAH
#undef STAGEH_B
#undef STAGEH_A

    // epilogue: per wave 64x64 output
#pragma unroll
    for (int mi = 0; mi < 4; ++mi) {
        const int row0 = tile_m + wmp * 64 + mi * 16 + quad * 4;
#pragma unroll
        for (int ni = 0; ni < 4; ++ni) {
            const int col = tile_n + wnp * 64 + ni * 16 + l16;
            float bv = 0.f, sc = 1.f;
            if (EPI == 4) {
                if (col < 2048)      { bv = bias[col];         sc = scale; }
                else if (col < 4096) { bv = bias2[col - 2048]; }
                else                 { bv = bias3[col - 4096]; }
            } else if (EPI != 5) {
                bv = bias[col];
            }
#pragma unroll
            for (int r = 0; r < 4; ++r) {
                const size_t idx = (size_t)(row0 + r) * N + col;
                float v = acc[mi][ni][r];
                if (EPI == 5) { atomicAdd(&((float*)C)[idx], v); continue; }
                v += bv;
                if (EPI == 1) v *= scale;
                if (EPI == 4) v *= sc;
                if (EPI == 2) v = 0.5f * v * (1.0f + erff(v * 0.70710678118f));
                if (EPI == 3) v += RESF32 ? ((const float*)res)[idx] : bf2f(((const bf16*)res)[idx]);
                if (OUTF32) ((float*)C)[idx] = v;
                else        ((bf16*)C)[idx] = f2bf(v);
            }
        }
    }
}

// ---- Flash attention v2 + head-colocating XCD swizzle (T1 for KV reuse) ---------------
// Each (b,h) head's K/V panel (512KB) is re-read by its 16 q-blocks. Default round-robin
// scatters them across XCDs -> ~512MB L2-miss traffic. Remap the 1024-block linear id
// bijectively so all 16 q-blocks of a head share lid%8 -> same XCD; per-XCD KV working
// set = 8 heads x 512KB = 4MB = L2 size -> 15/16 of KV reads become L2 hits.
__global__ __launch_bounds__(256)
void flash_attn(const bf16* __restrict__ QKV, const float* __restrict__ mask,
                bf16* __restrict__ O)
{
    __shared__ __align__(16) bf16 Ks[4 * 64 * 32];
    __shared__ __align__(16) bf16 Vt[128 * 72];
    __shared__ __align__(16) bf16 Ps[4][16 * 72];
    // bijective remap: lid = 10 bits -> xcd(3) | head-group(3) | qx(4)
    const int lid = blockIdx.x + blockIdx.y * 16;       // gridDim = (16, 64)
    const int j   = lid >> 3;
    const int bh  = (lid & 7) | ((j & 7) << 3);         // all 16 qx of a head: same lid%8
    const int qx  = j >> 3;
    const int b = bh >> 4, h = bh & 15;
    const int t = threadIdx.x, w = t >> 6, lane = t & 63, quad = lane >> 4, l16 = lane & 15;
    const int qbase = qx * 64 + w * 16;
    const size_t rowb = (size_t)b * Sc;
    const bf16* Kp = QKV + 2048 + (size_t)h * HDc;
    const bf16* Vp = QKV + 4096 + (size_t)h * HDc;

    short8 qf[4];
    {
        const bf16* qp = QKV + (rowb + qbase + l16) * QKVLD + (size_t)h * HDc + quad * 8;
#pragma unroll
        for (int kc = 0; kc < 4; ++kc) qf[kc] = *(const short8*)(qp + kc * 32);
    }
    float m_i[4], l_i[4];
    floatx4 Oacc[8] = {};
#pragma unroll
    for (int r = 0; r < 4; ++r) { m_i[r] = -1e30f; l_i[r] = 0.f; }

    const int p2 = t & 31, dg = t >> 5;

    for (int kt = 0; kt < Sc; kt += 64) {
        __syncthreads();
#pragma unroll
        for (int u = 0; u < 4; ++u) {
            const int row = u * 16 + (lane >> 2);
            glds16((char*)Ks + w * 4096 + u * 1024,
                   Kp + (rowb + kt + row) * QKVLD + w * 32 + (lane & 3) * 8);
        }
        {
            union { uint4 u4; unsigned short s[8]; } va[2][2];
#pragma unroll
            for (int kk = 0; kk < 2; ++kk) {
                const bf16* vp = Vp + (rowb + kt + 2 * p2 + kk) * QKVLD + dg * 16;
                va[kk][0].u4 = *(const uint4*)vp;
                va[kk][1].u4 = *(const uint4*)(vp + 8);
            }
            unsigned* VtW = (unsigned*)Vt;
#pragma unroll
            for (int j2 = 0; j2 < 16; ++j2) {
                const unsigned word = (unsigned)va[0][j2 >> 3].s[j2 & 7]
                                    | ((unsigned)va[1][j2 >> 3].s[j2 & 7] << 16);
                VtW[(dg * 16 + j2) * 36 + p2] = word;
            }
        }
        __syncthreads();

        floatx4 sacc[4] = {};
#pragma unroll
        for (int kc = 0; kc < 4; ++kc)
#pragma unroll
            for (int sub = 0; sub < 4; ++sub) {
                short8 kf = *(const short8*)&Ks[kc * 2048 + (sub * 16 + l16) * 32 + quad * 8];
                sacc[sub] = __builtin_amdgcn_mfma_f32_16x16x32_bf16(qf[kc], kf, sacc[sub], 0, 0, 0);
            }
#pragma unroll
        for (int sub = 0; sub < 4; ++sub) {
            const float mv = mask[b * Sc + kt + sub * 16 + l16];
            const float madd = (mv < 0.5f) ? -3.0e38f : 0.f;
#pragma unroll
            for (int r = 0; r < 4; ++r) sacc[sub][r] += madd;
        }
        float p[4][4], alpha[4];
#pragma unroll
        for (int r = 0; r < 4; ++r) {
            float mx = fmaxf(fmaxf(sacc[0][r], sacc[1][r]), fmaxf(sacc[2][r], sacc[3][r]));
#pragma unroll
            for (int off = 8; off; off >>= 1) mx = fmaxf(mx, __shfl_xor(mx, off));
            const float mnew = fmaxf(m_i[r], mx);
            alpha[r] = exp2f(m_i[r] - mnew);
            float ps = 0.f;
#pragma unroll
            for (int sub = 0; sub < 4; ++sub) { p[sub][r] = exp2f(sacc[sub][r] - mnew); ps += p[sub][r]; }
#pragma unroll
            for (int off = 8; off; off >>= 1) ps += __shfl_xor(ps, off);
            l_i[r] = l_i[r] * alpha[r] + ps;
            m_i[r] = mnew;
        }
#pragma unroll
        for (int nsub = 0; nsub < 8; ++nsub)
#pragma unroll
            for (int r = 0; r < 4; ++r) Oacc[nsub][r] *= alpha[r];

        bf16* Pw = Ps[w];
#pragma unroll
        for (int sub = 0; sub < 4; ++sub)
#pragma unroll
            for (int r = 0; r < 4; ++r)
                Pw[(quad * 4 + r) * 72 + sub * 16 + l16] = f2bf(p[sub][r]);
        const short8 pf0 = *(const short8*)&Pw[l16 * 72 + quad * 8];
        const short8 pf1 = *(const short8*)&Pw[l16 * 72 + 32 + quad * 8];
#pragma unroll
        for (int nsub = 0; nsub < 8; ++nsub) {
            const short8 vf0 = *(const short8*)&Vt[(nsub * 16 + l16) * 72 + quad * 8];
            const short8 vf1 = *(const short8*)&Vt[(nsub * 16 + l16) * 72 + 32 + quad * 8];
            Oacc[nsub] = __builtin_amdgcn_mfma_f32_16x16x32_bf16(pf0, vf0, Oacc[nsub], 0, 0, 0);
            Oacc[nsub] = __builtin_amdgcn_mfma_f32_16x16x32_bf16(pf1, vf1, Oacc[nsub], 0, 0, 0);
        }
    }

#pragma unroll
    for (int r = 0; r < 4; ++r) {
        const float inv = 1.f / l_i[r];
        bf16* orow = O + (rowb + qbase + quad * 4 + r) * Dc + (size_t)h * HDc;
#pragma unroll
        for (int nsub = 0; nsub < 8; ++nsub)
            orow[nsub * 16 + l16] = f2bf(Oacc[nsub][r] * inv);
    }
}

// ---------------------------------- launcher ------------------------------------------
extern "C" void kernel_launch(void* const* d_in, const int* in_sizes, int n_in,
                              void* d_out, int out_size, void* d_ws, size_t ws_size,
                              hipStream_t stream)
{
    const float* hidden = (const float*)d_in[1];
    const float* amask  = (const float*)d_in[2];
    const float* Wq = (const float*)d_in[4];  const float* bq = (const float*)d_in[5];
    const float* Wk = (const float*)d_in[6];  const float* bk = (const float*)d_in[7];
    const float* Wv = (const float*)d_in[8];  const float* bv = (const float*)d_in[9];
    const float* Wo = (const float*)d_in[10]; const float* bo = (const float*)d_in[11];
    const float* ln1w = (const float*)d_in[12]; const float* ln1b = (const float*)d_in[13];
    const float* ln2w = (const float*)d_in[14]; const float* ln2b = (const float*)d_in[15];
    const float* W1 = (const float*)d_in[16]; const float* b1 = (const float*)d_in[17];
    const float* W2 = (const float*)d_in[18]; const float* b2 = (const float*)d_in[19];

    const size_t UE = 8ull * 1024 * 1024;     // elements per 16 MB bf16 unit
    const size_t WE = 4ull * 1024 * 1024;     // elements per D*D weight
    bf16*  U = (bf16*)d_ws;
    bf16*  qkv   = U;                         // U0-U2 (48 MB) [4096][6144]
    bf16*  wbuf  = U + 4 * UE;                // U4-U5 (32 MB): Wq|Wk|Wv|Wo, then W1, then W2
    bf16*  x_ln  = U + 6 * UE;                // U6 (dead after QKV gemm)
    float* hid2f = (float*)(U + 6 * UE);      // U6-U7 fp32 32 MB (overlays x_ln)
    bf16*  ffn1  = U;                         // U0-U3 (64 MB; qkv dead)
    bf16*  attn  = (bf16*)d_out;              // d_out[0:16MB)
    bf16*  y_ln  = (bf16*)d_out + UE;         // d_out[16:32MB)
    float* outf  = (float*)d_out;

    const float qscale = 0.08838834764831845f * 1.4426950408889634f; // HD^-0.5 * log2e
    const dim3 gQKV(QKVLD / 256, Bc * Sc / 128, 1);  // (24,32) 768 blk = 3/CU exact
    const dim3 gWo (Dc / 256,    Bc * Sc / 128, 1);  // (8,32)  256 blk = 1/CU exact
    const dim3 gF1 (Ic / 256,    Bc * Sc / 256, 1);  // (32,16) 512 blk = 2/CU exact
    const dim3 gF2 (Dc / 256,    Bc * Sc / 128, 1);  // (8,32)  256 blk = 1/CU exact

    conv_w4<<<8192, 256, 0, stream>>>(Wq, Wk, Wv, Wo, wbuf);
    ln_kernel<1><<<Bc * Sc, 256, 0, stream>>>(hidden, ln1w, ln1b, x_ln);
    // QKV (fused bias + q-scale), balanced 128x256 grid
    gemm_bt_h<4,0,0><<<gQKV, 512, 0, stream>>>(x_ln, wbuf, bq, bk, bv, nullptr, qkv,
                                               Bc * Sc, QKVLD, Dc, qscale);
    flash_attn<<<dim3(Sc / 64, Bc * Hc), 256, 0, stream>>>(qkv, amask, attn);
    // hid2f = attn @ Wo^T + bo + hidden   (fused residual, fp32 out; no atomics)
    gemm_bt_h<3,1,1><<<gWo, 512, 0, stream>>>(attn, wbuf + 3 * WE, bo, nullptr, nullptr,
                                              hidden, hid2f, Bc * Sc, Dc, Dc, 0.f);
    ln_kernel<1><<<Bc * Sc, 256, 0, stream>>>(hid2f, ln2w, ln2b, y_ln);
    conv_w<<<8192, 256, 0, stream>>>(W1, wbuf);
    gemm_bt<2,0,0><<<gF1, 512, 0, stream>>>(y_ln, wbuf, b1, nullptr, nullptr, nullptr, ffn1,
                                            Bc * Sc, Ic, Dc, 0.f);
    conv_w<<<8192, 256, 0, stream>>>(W2, wbuf);
    // d_out = ffn1 @ W2^T + b2 + hid2f   (fused residual, fp32 out; no atomics)
    gemm_bt_h<3,1,1><<<gF2, 512, 0, stream>>>(ffn1, wbuf, b2, nullptr, nullptr,
                                              hid2f, outf, Bc * Sc, Dc, Ic, 0.f);
}